// Round 6
// baseline (817.873 us; speedup 1.0000x reference)
//
#include <hip/hip_runtime.h>
#include <stdint.h>

// ---------------------------------------------------------------------------
// ColorHead: quantize -> 11x11 mode pool -> (1x1conv+BN+LReLU)x2 ->
//            6-level stride-3 conv pyramid + nearest upsample + grouped 1x1
//            + per-level train-BN -> accumulated score (8,32,512,512) fp32.
// R7: R5 structure (744us, passed) + R4-validated k_modehist (mode + combo
//     hist in one kernel). 9 -> 8 GPU ops. Cooperative launch abandoned:
//     it is silently dropped under the harness's graph capture (R6 failure).
// ---------------------------------------------------------------------------

#define NPX   2097152          // 8*512*512
#define NINV  (1.0f/2097152.0f)

// ---- workspace layout (bytes) ----
#define OFF_STATS 0            // float stats[4096]
#define OFF_HIST  16384        // uint32 hist[4913]
#define OFF_LUT   36864        // uint32 lut[4913*8]  (16 bf16 per combo)
#define OFF_MODE  194560       // uint8 mode[8*3*512*512]
#define OFF_D1    73594880     // float d1[8*16*171*171]
#define OFF_D2    88566272     // float d2[8*16*57*57]
#define OFF_D3    90229760     // float d3[8*16*19*19]
#define OFF_D4    90414592     // float d4[8*16*7*7]
#define OFF_D5    90439680     // float d5[8*16*3*3]
#define OFF_D6    90444288     // float d6[8*16*1*1]

// ---- stats region (float indices) ----
#define S_PRE1    0     // 16
#define S2_PRE1   16    // 16
#define S_H1      32    // 16
#define S_H1H1    48    // 136 (upper tri raw second moments)
#define S_PREP    184   // 16
#define S2_PREP   200   // 16
#define S_Z1      216   // 16  (+S2_Z1 232, S_PZ1 248: 48 contiguous)
#define S2_Z1     232
#define S_PZ1     248
#define S_LVLBASE 264   // levels 2..6: 48 each {Sz,Sz2,Szz}
#define P_A1      512   // 48
#define P_B1      560   // 16
#define P_A2      576   // 256
#define P_B2      832   // 16

__device__ __forceinline__ uint32_t f2bf(float f) {
  uint32_t u = __float_as_uint(f);
  u += 0x7FFFu + ((u >> 16) & 1u);
  return u >> 16;
}
__device__ __forceinline__ float bf2f(uint32_t u) {
  return __uint_as_float(u << 16);
}

__device__ __forceinline__ float wave_red(float v) {
  v += __shfl_down(v, 32); v += __shfl_down(v, 16); v += __shfl_down(v, 8);
  v += __shfl_down(v, 4);  v += __shfl_down(v, 2);  v += __shfl_down(v, 1);
  return v;
}

// block = 256 threads. Reduce K per-thread partials, then atomic/store.
template<int K, bool ATOMIC>
__device__ __forceinline__ void block_red(float* acc, float* dst, float* lds) {
  int lane = threadIdx.x & 63, wid = threadIdx.x >> 6;
#pragma unroll
  for (int k = 0; k < K; ++k) {
    float v = wave_red(acc[k]);
    if (lane == 0) lds[wid * K + k] = v;
  }
  __syncthreads();
  if ((int)threadIdx.x < K) {
    float s = lds[threadIdx.x] + lds[K + threadIdx.x] + lds[2 * K + threadIdx.x] + lds[3 * K + threadIdx.x];
    if (ATOMIC) atomicAdd(&dst[threadIdx.x], s);
    else        dst[threadIdx.x] = s;
  }
}

// ---- packed 17-bin byte counters in 5 dwords ----
__device__ __forceinline__ void hadd(uint32_t* h, int v) {
  uint32_t inc = 1u << ((v & 3) << 3); int w = v >> 2;
#pragma unroll
  for (int k = 0; k < 5; ++k) h[k] += (w == k) ? inc : 0u;
}
__device__ __forceinline__ void hsub(uint32_t* h, int v) {
  uint32_t inc = 1u << ((v & 3) << 3); int w = v >> 2;
#pragma unroll
  for (int k = 0; k < 5; ++k) h[k] -= (w == k) ? inc : 0u;
}
__device__ __forceinline__ int hscan(const uint32_t* h) {
  uint32_t best = h[0] & 255u; int bi = 0;
#pragma unroll
  for (int k = 1; k < 17; ++k) {
    uint32_t c = (h[k >> 2] >> ((k & 3) << 3)) & 255u;
    if (c > best) { best = c; bi = k; }  // strict > : first max (torch tie-break)
  }
  return bi;
}

// ---------------------------------------------------------------------------
// K1: quantize + 11x11 reflect-padded mode pool, ALL 3 CHANNELS per block,
//     plus combo histogram (17^3 bins). grid 256 = (16 rowblk, 2 colblk, 8 b).
//     Validated in R4's passing run.
// ---------------------------------------------------------------------------
__global__ __launch_bounds__(256) void k_modehist(const float* __restrict__ x,
                                                  uint8_t* __restrict__ mode,
                                                  uint32_t* __restrict__ hist) {
  int bx = blockIdx.x;
  int rb = bx & 15, cb = (bx >> 4) & 1, b = bx >> 5;
  __shared__ uint8_t tile[3][42][272];
  __shared__ uint32_t lh[4913];
  int tid = threadIdx.x;
  for (int e = tid; e < 4913; e += 256) lh[e] = 0;
  const float* xb = x + (size_t)b * 786432;
  for (int e = tid; e < 3 * 42 * 266; e += 256) {
    int ch = e / (42 * 266); int rem = e - ch * (42 * 266);
    int lr = rem / 266, lc = rem - lr * 266;
    int gr = rb * 32 - 5 + lr; if (gr < 0) gr = -gr; else if (gr > 511) gr = 1022 - gr;
    int gc = cb * 256 - 5 + lc; if (gc < 0) gc = -gc; else if (gc > 511) gc = 1022 - gc;
    float v = xb[(size_t)ch * 262144 + gr * 512 + gc];
    tile[ch][lr][lc] = (uint8_t)(int)rintf((v * 255.0f) * 0.0625f);
  }
  __syncthreads();
  int t = tid;
  uint32_t h[3][5];
#pragma unroll
  for (int ch = 0; ch < 3; ++ch)
#pragma unroll
    for (int k = 0; k < 5; ++k) h[ch][k] = 0;
#pragma unroll
  for (int dy = 0; dy < 11; ++dy)
#pragma unroll
    for (int dx = 0; dx < 11; ++dx) {
      hadd(h[0], tile[0][dy][t + dx]);
      hadd(h[1], tile[1][dy][t + dx]);
      hadd(h[2], tile[2][dy][t + dx]);
    }
  size_t ob = (size_t)b * 786432 + (size_t)(rb * 32) * 512 + cb * 256 + t;
  {
    int m0 = hscan(h[0]), m1 = hscan(h[1]), m2 = hscan(h[2]);
    mode[ob] = (uint8_t)m0; mode[ob + 262144] = (uint8_t)m1; mode[ob + 524288] = (uint8_t)m2;
    atomicAdd(&lh[m0 + 17 * m1 + 289 * m2], 1u);
  }
  for (int s = 1; s < 32; ++s) {
#pragma unroll
    for (int dx = 0; dx < 11; ++dx) {
      hsub(h[0], tile[0][s - 1][t + dx]); hadd(h[0], tile[0][s + 10][t + dx]);
      hsub(h[1], tile[1][s - 1][t + dx]); hadd(h[1], tile[1][s + 10][t + dx]);
      hsub(h[2], tile[2][s - 1][t + dx]); hadd(h[2], tile[2][s + 10][t + dx]);
    }
    size_t o = ob + (size_t)s * 512;
    int m0 = hscan(h[0]), m1 = hscan(h[1]), m2 = hscan(h[2]);
    mode[o] = (uint8_t)m0; mode[o + 262144] = (uint8_t)m1; mode[o + 524288] = (uint8_t)m2;
    atomicAdd(&lh[m0 + 17 * m1 + 289 * m2], 1u);
  }
  __syncthreads();
  for (int e = tid; e < 4913; e += 256)
    if (lh[e]) atomicAdd(&hist[e], lh[e]);
}

// ---------------------------------------------------------------------------
// K2: one-block build: pre1 moments -> BN1 -> h1 moments -> BN2 -> LUT + prep
//     moments. Everything weighted by the combo histogram.
// ---------------------------------------------------------------------------
__global__ __launch_bounds__(256) void k_build(const uint32_t* __restrict__ hist,
    const float* __restrict__ pw1, const float* __restrict__ pb1,
    const float* __restrict__ g1,  const float* __restrict__ be1,
    const float* __restrict__ pw2, const float* __restrict__ pb2,
    const float* __restrict__ g2,  const float* __restrict__ be2,
    float* __restrict__ stats, uint32_t* __restrict__ lut) {
  __shared__ float red[4 * 152];
  int tid = threadIdx.x;
  {
    float acc[32];
#pragma unroll
    for (int k = 0; k < 32; ++k) acc[k] = 0.f;
    for (int bin = tid; bin < 4913; bin += 256) {
      float w = (float)hist[bin];
      if (w == 0.f) continue;
      int m0 = bin % 17, r = bin / 17;
      int m1 = r % 17, m2 = r / 17;
      float x0 = m0 * 0.0625f, x1 = m1 * 0.0625f, x2 = m2 * 0.0625f;
#pragma unroll
      for (int o = 0; o < 16; ++o) {
        float p = fmaf(pw1[o * 3], x0, fmaf(pw1[o * 3 + 1], x1, fmaf(pw1[o * 3 + 2], x2, pb1[o])));
        acc[o] = fmaf(w, p, acc[o]);
        acc[16 + o] = fmaf(w * p, p, acc[16 + o]);
      }
    }
    block_red<32, false>(acc, stats + S_PRE1, red);
  }
  __syncthreads();
  if (tid < 16) {
    int o = tid;
    float m = stats[S_PRE1 + o] * NINV;
    float var = stats[S2_PRE1 + o] * NINV - m * m;
    float s = g1[o] * rsqrtf(var + 1e-5f);
    stats[P_A1 + o * 3 + 0] = pw1[o * 3 + 0] * s;
    stats[P_A1 + o * 3 + 1] = pw1[o * 3 + 1] * s;
    stats[P_A1 + o * 3 + 2] = pw1[o * 3 + 2] * s;
    stats[P_B1 + o] = (pb1[o] - m) * s + be1[o];
  }
  __syncthreads();
  {
    float acc[152];
#pragma unroll
    for (int k = 0; k < 152; ++k) acc[k] = 0.f;
    for (int bin = tid; bin < 4913; bin += 256) {
      float w = (float)hist[bin];
      if (w == 0.f) continue;
      int m0 = bin % 17, r = bin / 17;
      int m1 = r % 17, m2 = r / 17;
      float x0 = m0 * 0.0625f, x1 = m1 * 0.0625f, x2 = m2 * 0.0625f;
      float h[16];
#pragma unroll
      for (int c = 0; c < 16; ++c) {
        float y = fmaf(stats[P_A1 + c * 3], x0, fmaf(stats[P_A1 + c * 3 + 1], x1,
                  fmaf(stats[P_A1 + c * 3 + 2], x2, stats[P_B1 + c])));
        h[c] = fmaxf(y, 0.01f * y);
        acc[c] = fmaf(w, h[c], acc[c]);
      }
#pragma unroll
      for (int c = 0; c < 16; ++c) {
#pragma unroll
        for (int c2 = c; c2 < 16; ++c2) {
          int idx = 16 * c - (c * (c - 1)) / 2 + (c2 - c);
          acc[16 + idx] = fmaf(w * h[c], h[c2], acc[16 + idx]);
        }
      }
    }
    block_red<152, false>(acc, stats + S_H1, red);
  }
  __syncthreads();
  if (tid < 16) {
    int o = tid;
    float s1 = 0.f;
#pragma unroll
    for (int c = 0; c < 16; ++c) s1 = fmaf(pw2[o * 16 + c], stats[S_H1 + c] * NINV, s1);
    float e2 = 0.f;
#pragma unroll
    for (int c = 0; c < 16; ++c) {
#pragma unroll
      for (int c2 = 0; c2 < 16; ++c2) {
        int lo = c < c2 ? c : c2, hi = c < c2 ? c2 : c;
        int idx = 16 * lo - (lo * (lo - 1)) / 2 + (hi - lo);
        e2 = fmaf(pw2[o * 16 + c] * pw2[o * 16 + c2], stats[S_H1H1 + idx] * NINV, e2);
      }
    }
    float var = e2 - s1 * s1;
    float mean = s1 + pb2[o];
    float s = g2[o] * rsqrtf(var + 1e-5f);
#pragma unroll
    for (int c = 0; c < 16; ++c) stats[P_A2 + o * 16 + c] = pw2[o * 16 + c] * s;
    stats[P_B2 + o] = (pb2[o] - mean) * s + be2[o];
  }
  __syncthreads();
  {
    float acc[32];
#pragma unroll
    for (int k = 0; k < 32; ++k) acc[k] = 0.f;
    for (int bin = tid; bin < 4913; bin += 256) {
      float w = (float)hist[bin];
      int m0 = bin % 17, r = bin / 17;
      int m1 = r % 17, m2 = r / 17;
      float x0 = m0 * 0.0625f, x1 = m1 * 0.0625f, x2 = m2 * 0.0625f;
      float h[16];
#pragma unroll
      for (int c = 0; c < 16; ++c) {
        float y = fmaf(stats[P_A1 + c * 3], x0, fmaf(stats[P_A1 + c * 3 + 1], x1,
                  fmaf(stats[P_A1 + c * 3 + 2], x2, stats[P_B1 + c])));
        h[c] = fmaxf(y, 0.01f * y);
      }
      float p[16];
#pragma unroll
      for (int o = 0; o < 16; ++o) {
        float y = stats[P_B2 + o];
#pragma unroll
        for (int c = 0; c < 16; ++c) y = fmaf(stats[P_A2 + o * 16 + c], h[c], y);
        p[o] = fmaxf(y, 0.01f * y);
        acc[o] = fmaf(w, p[o], acc[o]);
        acc[16 + o] = fmaf(w * p[o], p[o], acc[16 + o]);
      }
#pragma unroll
      for (int d = 0; d < 8; ++d)
        lut[bin * 8 + d] = f2bf(p[2 * d]) | (f2bf(p[2 * d + 1]) << 16);
    }
    block_red<32, false>(acc, stats + S_PREP, red);
  }
}

// ---------------------------------------------------------------------------
// conv body: 3x3 stride 3 pad 1, 16->16 channels, fp32 in/out.
// ---------------------------------------------------------------------------
template<int HIN, int WIN, int HOUT, int WOUT>
__device__ __forceinline__ void conv_body(const float* __restrict__ in,
                                          float* __restrict__ out,
                                          const float* __restrict__ dw, int bx) {
  __shared__ float tile[3][16][WIN + 2];
  int r = bx % HOUT, b = bx / HOUT;
  int tid = threadIdx.x;
  for (int e = tid; e < 48; e += 256) { tile[e / 16][e & 15][0] = 0.f; tile[e / 16][e & 15][WIN + 1] = 0.f; }
  for (int e = tid; e < 3 * 16 * WIN; e += 256) {
    int ky = e / (16 * WIN); int rem = e - ky * (16 * WIN); int ic = rem / WIN; int col = rem - ic * WIN;
    int gr = 3 * r - 1 + ky;
    float v = 0.f;
    if (gr >= 0 && gr < HIN) v = in[((size_t)(b * 16 + ic) * HIN + gr) * WIN + col];
    tile[ky][ic][col + 1] = v;
  }
  __syncthreads();
  int c = tid;
  if (c < WOUT) {
    float acc[16];
#pragma unroll
    for (int o = 0; o < 16; ++o) acc[o] = 0.f;
#pragma unroll
    for (int ic = 0; ic < 16; ++ic) {
      float v[9];
#pragma unroll
      for (int ky = 0; ky < 3; ++ky) {
#pragma unroll
        for (int kx = 0; kx < 3; ++kx) v[ky * 3 + kx] = tile[ky][ic][3 * c + kx];
      }
#pragma unroll
      for (int o = 0; o < 16; ++o) {
        const float* w = dw + (o * 16 + ic) * 9;
#pragma unroll
        for (int tp = 0; tp < 9; ++tp) acc[o] = fmaf(v[tp], w[tp], acc[o]);
      }
    }
#pragma unroll
    for (int o = 0; o < 16; ++o)
      out[((size_t)(b * 16 + o) * HOUT + r) * WOUT + c] = acc[o];
  }
}

// pair stats body: Sz, Sz^2, S(z_{l-1} z_l) over dst grid. 512 blocks' worth.
template<int HP, int HZ>
__device__ __forceinline__ void pair_body(const float* __restrict__ dp,
                                          const float* __restrict__ dz,
                                          float* __restrict__ dst, int bx) {
  int g = bx & 15, b = (bx >> 4) & 7, jq = bx >> 7;
  const float* dpp = dp + (size_t)(b * 16 + g) * HP * HP;
  const float* dzp = dz + (size_t)(b * 16 + g) * HZ * HZ;
  float a1 = 0.f, a2 = 0.f, a3 = 0.f;
  for (int j = jq * 128; j < jq * 128 + 128; ++j) {
    int r1 = (j * HP) >> 9, r2 = (j * HZ) >> 9;
    const float* rp = dpp + r1 * HP;
    const float* rz = dzp + r2 * HZ;
    for (int i = threadIdx.x; i < 512; i += 256) {
      int c1 = (i * HP) >> 9, c2 = (i * HZ) >> 9;
      float zp = rp[c1], zz = rz[c2];
      a1 += zz; a2 = fmaf(zz, zz, a2); a3 = fmaf(zp, zz, a3);
    }
  }
  a1 = wave_red(a1); a2 = wave_red(a2); a3 = wave_red(a3);
  __shared__ float red[12];
  int lane = threadIdx.x & 63, wid = threadIdx.x >> 6;
  if (!lane) { red[wid * 3] = a1; red[wid * 3 + 1] = a2; red[wid * 3 + 2] = a3; }
  __syncthreads();
  if (threadIdx.x < 3) {
    float s = red[threadIdx.x] + red[3 + threadIdx.x] + red[6 + threadIdx.x] + red[9 + threadIdx.x];
    atomicAdd(&dst[threadIdx.x * 16 + g], s);
  }
}

// level-1 stats body: Sz1, Sz1^2, S(prep*z1); prep gathered from mode+LUT.
__device__ __forceinline__ void corr1_body(const uint8_t* __restrict__ mode,
                                           const uint32_t* __restrict__ lut,
                                           const float* __restrict__ d1,
                                           float* __restrict__ stats, int bx) {
  int b = bx >> 6, band = bx & 63;
  float acc[48];
#pragma unroll
  for (int k = 0; k < 48; ++k) acc[k] = 0.f;
  for (int jj = 0; jj < 8; ++jj) {
    int j = band * 8 + jj;
    int r1 = (j * 171) >> 9;
#pragma unroll
    for (int ii = 0; ii < 2; ++ii) {
      int i = (int)threadIdx.x + ii * 256;
      int c1 = (i * 171) >> 9;
      const uint8_t* mp = mode + (size_t)b * 786432 + j * 512 + i;
      int combo = (int)mp[0] + 17 * (int)mp[262144] + 289 * (int)mp[524288];
      const uint4* L = (const uint4*)(lut + combo * 8);
      uint4 q0 = L[0], q1 = L[1];
      uint32_t q[8] = {q0.x, q0.y, q0.z, q0.w, q1.x, q1.y, q1.z, q1.w};
#pragma unroll
      for (int g = 0; g < 16; ++g) {
        float p = bf2f((g & 1) ? (q[g >> 1] >> 16) : (q[g >> 1] & 0xFFFFu));
        float z = d1[((size_t)(b * 16 + g) * 171 + r1) * 171 + c1];
        acc[g] += z; acc[16 + g] = fmaf(z, z, acc[16 + g]); acc[32 + g] = fmaf(p, z, acc[32 + g]);
      }
    }
  }
  __shared__ float red[4 * 48];
  block_red<48, true>(acc, stats + S_Z1, red);
}

// ---------------------------------------------------------------------------
// K3: level-1 conv, input gathered from mode+LUT (bf16 LUT lines, L2-resident).
// ---------------------------------------------------------------------------
__global__ __launch_bounds__(256) void k_conv1g(const uint8_t* __restrict__ mode,
                                                const uint32_t* __restrict__ lut,
                                                float* __restrict__ out,
                                                const float* __restrict__ dw) {
  __shared__ uint16_t tile[3][16][514];
  int bx = blockIdx.x; int r = bx % 171, b = bx / 171;
  int tid = threadIdx.x;
  for (int e = tid; e < 48; e += 256) { tile[e / 16][e & 15][0] = 0; tile[e / 16][e & 15][513] = 0; }
  for (int e = tid; e < 3 * 512; e += 256) {
    int ky = e >> 9, col = e & 511;
    int gr = 3 * r - 1 + ky;
    if (gr < 0 || gr > 511) {
#pragma unroll
      for (int c = 0; c < 16; ++c) tile[ky][c][col + 1] = 0;
    } else {
      const uint8_t* mp = mode + (size_t)b * 786432 + gr * 512 + col;
      int combo = (int)mp[0] + 17 * (int)mp[262144] + 289 * (int)mp[524288];
      const uint4* L = (const uint4*)(lut + combo * 8);
      uint4 q0 = L[0], q1 = L[1];
      uint32_t q[8] = {q0.x, q0.y, q0.z, q0.w, q1.x, q1.y, q1.z, q1.w};
#pragma unroll
      for (int d = 0; d < 8; ++d) {
        tile[ky][2 * d][col + 1]     = (uint16_t)(q[d] & 0xFFFFu);
        tile[ky][2 * d + 1][col + 1] = (uint16_t)(q[d] >> 16);
      }
    }
  }
  __syncthreads();
  int c = tid;
  if (c < 171) {
    float acc[16];
#pragma unroll
    for (int o = 0; o < 16; ++o) acc[o] = 0.f;
#pragma unroll
    for (int ic = 0; ic < 16; ++ic) {
      float v[9];
#pragma unroll
      for (int ky = 0; ky < 3; ++ky) {
#pragma unroll
        for (int kx = 0; kx < 3; ++kx)
          v[ky * 3 + kx] = __uint_as_float(((uint32_t)tile[ky][ic][3 * c + kx]) << 16);
      }
#pragma unroll
      for (int o = 0; o < 16; ++o) {
        const float* w = dw + (o * 16 + ic) * 9;
#pragma unroll
        for (int tp = 0; tp < 9; ++tp) acc[o] = fmaf(v[tp], w[tp], acc[o]);
      }
    }
#pragma unroll
    for (int o = 0; o < 16; ++o)
      out[((size_t)(b * 16 + o) * 171 + r) * 171 + c] = acc[o];
  }
}

// K4: conv level 2 (456 blocks) + corr1 stats (512 blocks) in one dispatch.
__global__ __launch_bounds__(256) void k_conv2_corr1(const float* __restrict__ d1,
    float* __restrict__ d2, const float* __restrict__ dw,
    const uint8_t* __restrict__ mode, const uint32_t* __restrict__ lut,
    float* __restrict__ stats) {
  if ((int)blockIdx.x < 456) conv_body<171, 171, 57, 57>(d1, d2, dw, (int)blockIdx.x);
  else                       corr1_body(mode, lut, d1, stats, (int)blockIdx.x - 456);
}

// K5: conv level 3 (152 blocks) + pair stats for level 2 (512 blocks).
__global__ __launch_bounds__(256) void k_conv3_pair(const float* __restrict__ d2,
    float* __restrict__ d3, const float* __restrict__ dw,
    const float* __restrict__ d1, float* __restrict__ stats) {
  if ((int)blockIdx.x < 152) conv_body<57, 57, 19, 19>(d2, d3, dw, (int)blockIdx.x);
  else                       pair_body<171, 57>(d1, d2, stats + S_LVLBASE, (int)blockIdx.x - 152);
}

// ---------------------------------------------------------------------------
// K6: k_tail8: blocks 0..7 = per-batch {conv4, pair4-exact, conv5, pair5-exact,
//     conv6, pair6-closed} with dw cached in LDS; blocks 8..519 = pair<57,19>
//     rider for level-3 stats.
// ---------------------------------------------------------------------------
__global__ __launch_bounds__(256) void k_tail8(const float* __restrict__ d2,
    const float* __restrict__ d3, float* __restrict__ d4, float* __restrict__ d5,
    float* __restrict__ d6, const float* __restrict__ dw, float* __restrict__ stats) {
  int bx = blockIdx.x;
  if (bx >= 8) { pair_body<57, 19>(d2, d3, stats + S_LVLBASE + 48, bx - 8); return; }
  __shared__ float s3[16][19][19];
  __shared__ float s4[16][7][7];
  __shared__ float s5[16][3][3];
  __shared__ float s6[16];
  __shared__ float dwS[2304];
  __shared__ float acc[144];   // {Sz4,Sz4²,Sz3z4}[48] {z5..}[48] {z6..}[48]
  int tid = threadIdx.x, b = bx;
  for (int e = tid; e < 2304; e += 256) dwS[e] = dw[e];
  for (int e = tid; e < 144; e += 256) acc[e] = 0.f;
  for (int e = tid; e < 16 * 361; e += 256) ((float*)s3)[e] = d3[(size_t)b * 5776 + e];
  __syncthreads();
  // conv4: d3(19) -> d4(7)
  for (int e = tid; e < 784; e += 256) {
    int o = e / 49, rc = e - o * 49; int r = rc / 7, c = rc % 7;
    float a = 0.f;
#pragma unroll
    for (int ic = 0; ic < 16; ++ic) {
      const float* w = dwS + (o * 16 + ic) * 9;
#pragma unroll
      for (int ky = 0; ky < 3; ++ky) {
        int gr = 3 * r - 1 + ky; if (gr < 0 || gr > 18) continue;
#pragma unroll
        for (int kx = 0; kx < 3; ++kx) {
          int gc = 3 * c - 1 + kx; if (gc < 0 || gc > 18) continue;
          a = fmaf(s3[ic][gr][gc], w[ky * 3 + kx], a);
        }
      }
    }
    s4[o][r][c] = a; d4[((size_t)(b * 16 + o) * 7 + r) * 7 + c] = a;
  }
  __syncthreads();
  // pair4 (19 -> 7) exact counts ; conv5: s4 -> s5, d5
  for (int e = tid; e < 784; e += 256) {
    int g = e & 15, rc = e >> 4; int r2 = rc / 7, c2 = rc % 7;
    int loZ = (512 * r2 + 6) / 7, hiZ = (512 * (r2 + 1) + 6) / 7;
    int loC = (512 * c2 + 6) / 7, hiC = (512 * (c2 + 1) + 6) / 7;
    int rrmin = (loZ * 19) >> 9, rrmax = ((hiZ - 1) * 19) >> 9;
    int ccmin = (loC * 19) >> 9, ccmax = ((hiC - 1) * 19) >> 9;
    float z = s4[g][r2][c2];
    float B = 0.f;
    for (int rr = rrmin; rr <= rrmax; ++rr) {
      int loP = (512 * rr + 18) / 19, hiP = (512 * (rr + 1) + 18) / 19;
      int cntR = min(hiP, hiZ) - max(loP, loZ); if (cntR <= 0) continue;
      float rowS = 0.f;
      for (int cc = ccmin; cc <= ccmax; ++cc) {
        int loQ = (512 * cc + 18) / 19, hiQ = (512 * (cc + 1) + 18) / 19;
        int cntC = min(hiQ, hiC) - max(loQ, loC); if (cntC <= 0) continue;
        rowS = fmaf((float)cntC, s3[g][rr][cc], rowS);
      }
      B = fmaf((float)cntR, rowS, B);
    }
    float wgt = (float)((hiZ - loZ) * (hiC - loC));
    atomicAdd(&acc[g], wgt * z);
    atomicAdd(&acc[16 + g], wgt * z * z);
    atomicAdd(&acc[32 + g], B * z);
  }
  for (int e = tid; e < 144; e += 256) {
    int o = e / 9, rc = e - o * 9; int r = rc / 3, c = rc % 3;
    float a = 0.f;
#pragma unroll
    for (int ic = 0; ic < 16; ++ic) {
      const float* w = dwS + (o * 16 + ic) * 9;
#pragma unroll
      for (int ky = 0; ky < 3; ++ky) {
        int gr = 3 * r - 1 + ky; if (gr < 0 || gr > 6) continue;
#pragma unroll
        for (int kx = 0; kx < 3; ++kx) {
          int gc = 3 * c - 1 + kx; if (gc < 0 || gc > 6) continue;
          a = fmaf(s4[ic][gr][gc], w[ky * 3 + kx], a);
        }
      }
    }
    s5[o][r][c] = a; d5[((size_t)(b * 16 + o) * 3 + r) * 3 + c] = a;
  }
  __syncthreads();
  // pair5 (7 -> 3) exact counts ; conv6: s5 -> s6, d6
  for (int e = tid; e < 144; e += 256) {
    int g = e & 15, rc = e >> 4; int r2 = rc / 3, c2 = rc % 3;
    int loZ = (512 * r2 + 2) / 3, hiZ = (512 * (r2 + 1) + 2) / 3;
    int loC = (512 * c2 + 2) / 3, hiC = (512 * (c2 + 1) + 2) / 3;
    int rrmin = (loZ * 7) >> 9, rrmax = ((hiZ - 1) * 7) >> 9;
    int ccmin = (loC * 7) >> 9, ccmax = ((hiC - 1) * 7) >> 9;
    float z = s5[g][r2][c2];
    float B = 0.f;
    for (int rr = rrmin; rr <= rrmax; ++rr) {
      int loP = (512 * rr + 6) / 7, hiP = (512 * (rr + 1) + 6) / 7;
      int cntR = min(hiP, hiZ) - max(loP, loZ); if (cntR <= 0) continue;
      float rowS = 0.f;
      for (int cc = ccmin; cc <= ccmax; ++cc) {
        int loQ = (512 * cc + 6) / 7, hiQ = (512 * (cc + 1) + 6) / 7;
        int cntC = min(hiQ, hiC) - max(loQ, loC); if (cntC <= 0) continue;
        rowS = fmaf((float)cntC, s4[g][rr][cc], rowS);
      }
      B = fmaf((float)cntR, rowS, B);
    }
    float wgt = (float)((hiZ - loZ) * (hiC - loC));
    atomicAdd(&acc[48 + g], wgt * z);
    atomicAdd(&acc[64 + g], wgt * z * z);
    atomicAdd(&acc[80 + g], B * z);
  }
  if (tid < 16) {
    int o = tid; float a = 0.f;
#pragma unroll
    for (int ic = 0; ic < 16; ++ic) {
      const float* w = dwS + (o * 16 + ic) * 9;
#pragma unroll
      for (int ky = 1; ky < 3; ++ky)
#pragma unroll
        for (int kx = 1; kx < 3; ++kx)
          a = fmaf(s5[ic][ky - 1][kx - 1], w[ky * 3 + kx], a);
    }
    s6[o] = a; d6[b * 16 + o] = a;
  }
  __syncthreads();
  // pair6 (3 -> 1) closed form: z6 constant; nearest weights 171/171/170
  if (tid < 16) {
    int g = tid; float z6 = s6[g];
    const float wr3[3] = {171.f, 171.f, 170.f};
    float s5s = 0.f;
#pragma unroll
    for (int r = 0; r < 3; ++r)
#pragma unroll
      for (int c = 0; c < 3; ++c) s5s = fmaf(wr3[r] * wr3[c], s5[g][r][c], s5s);
    acc[96 + g]  += 262144.f * z6;
    acc[112 + g] += 262144.f * z6 * z6;
    acc[128 + g] += z6 * s5s;
  }
  __syncthreads();
  for (int e = tid; e < 144; e += 256)
    atomicAdd(&stats[S_LVLBASE + 96 + e], acc[e]);
}

// ---------------------------------------------------------------------------
// K7: fused score: BN affines computed in-block from raw sums, then all 6
//     levels in one pass. grid 4096 = (b, row j).
// ---------------------------------------------------------------------------
__global__ __launch_bounds__(256) void k_score(const uint8_t* __restrict__ mode,
    const uint32_t* __restrict__ lut,
    const float* __restrict__ d1, const float* __restrict__ d2, const float* __restrict__ d3,
    const float* __restrict__ d4, const float* __restrict__ d5, const float* __restrict__ d6,
    const float* __restrict__ stats, const float* __restrict__ sw,
    const float* __restrict__ gs, const float* __restrict__ bs,
    float* __restrict__ out) {
  __shared__ float zrow[4128];
  __shared__ float aff[576];
  __shared__ uint16_t prow[16][512];
  int bx = blockIdx.x; int b = bx >> 9, j = bx & 511;
  int tid = threadIdx.x;
  // BN affines from raw sums (~25 flops/thread, redundant per block but free)
  if (tid < 192) {
    int lvl = tid >> 5, ch = tid & 31, g = ch >> 1, o = ch & 1;
    float Sp, Sp2, Sz, Sz2, Spz;
    if (lvl == 0) {
      Sp = stats[S_PREP + g]; Sp2 = stats[S2_PREP + g];
      Sz = stats[S_Z1 + g];   Sz2 = stats[S2_Z1 + g]; Spz = stats[S_PZ1 + g];
    } else {
      int base = S_LVLBASE + (lvl - 1) * 48;
      Sz = stats[base + g]; Sz2 = stats[base + 16 + g]; Spz = stats[base + 32 + g];
      if (lvl == 1) { Sp = stats[S_Z1 + g]; Sp2 = stats[S2_Z1 + g]; }
      else { int pb = S_LVLBASE + (lvl - 2) * 48; Sp = stats[pb + g]; Sp2 = stats[pb + 16 + g]; }
    }
    float mp = Sp * NINV, mz = Sz * NINV;
    float ep2 = Sp2 * NINV, ez2 = Sz2 * NINV, epz = Spz * NINV;
    float w0 = sw[g * 4 + o * 2], w1 = sw[g * 4 + o * 2 + 1];
    float mean = w0 * mp + w1 * mz;
    float e2 = w0 * w0 * ep2 + 2.f * w0 * w1 * epz + w1 * w1 * ez2;
    float var = e2 - mean * mean;
    float s = gs[ch] * rsqrtf(var + 1e-5f);
    aff[(lvl * 32 + ch) * 3 + 0] = s * w0;
    aff[(lvl * 32 + ch) * 3 + 1] = s * w1;
    aff[(lvl * 32 + ch) * 3 + 2] = bs[ch] - mean * s;
  }
  {
    const uint8_t* mp = mode + (size_t)b * 786432 + j * 512 + tid * 2;
    uint32_t m0 = *(const uint16_t*)(mp);
    uint32_t m1 = *(const uint16_t*)(mp + 262144);
    uint32_t m2 = *(const uint16_t*)(mp + 524288);
    int ca = (int)(m0 & 255u) + 17 * (int)(m1 & 255u) + 289 * (int)(m2 & 255u);
    int cb = (int)(m0 >> 8)   + 17 * (int)(m1 >> 8)   + 289 * (int)(m2 >> 8);
    const uint4* La = (const uint4*)(lut + ca * 8);
    const uint4* Lb = (const uint4*)(lut + cb * 8);
    uint4 a0 = La[0], a1 = La[1], b0 = Lb[0], b1 = Lb[1];
    uint32_t pa[8] = {a0.x, a0.y, a0.z, a0.w, a1.x, a1.y, a1.z, a1.w};
    uint32_t pb[8] = {b0.x, b0.y, b0.z, b0.w, b1.x, b1.y, b1.z, b1.w};
    uint32_t* pr32 = (uint32_t*)prow;
#pragma unroll
    for (int c = 0; c < 16; ++c) {
      uint32_t lo = (c & 1) ? (pa[c >> 1] >> 16)         : (pa[c >> 1] & 0xFFFFu);
      uint32_t hi = (c & 1) ? (pb[c >> 1] & 0xFFFF0000u) : (pb[c >> 1] << 16);
      pr32[c * 256 + tid] = lo | hi;
    }
  }
  { int r = (j * 171) >> 9; for (int e = tid; e < 16 * 171; e += 256) { int g = e / 171, c = e - g * 171; zrow[e]        = d1[((size_t)(b * 16 + g) * 171 + r) * 171 + c]; } }
  { int r = (j * 57)  >> 9; for (int e = tid; e < 16 * 57;  e += 256) { int g = e / 57,  c = e - g * 57;  zrow[2736 + e] = d2[((size_t)(b * 16 + g) * 57  + r) * 57  + c]; } }
  { int r = (j * 19)  >> 9; for (int e = tid; e < 16 * 19;  e += 256) { int g = e / 19,  c = e - g * 19;  zrow[3648 + e] = d3[((size_t)(b * 16 + g) * 19  + r) * 19  + c]; } }
  { int r = (j * 7)   >> 9; for (int e = tid; e < 16 * 7;   e += 256) { int g = e / 7,   c = e - g * 7;   zrow[3952 + e] = d4[((size_t)(b * 16 + g) * 7   + r) * 7   + c]; } }
  { int r = (j * 3)   >> 9; for (int e = tid; e < 16 * 3;   e += 256) { int g = e / 3,   c = e - g * 3;   zrow[4064 + e] = d5[((size_t)(b * 16 + g) * 3   + r) * 3   + c]; } }
  { for (int e = tid; e < 16; e += 256) zrow[4112 + e] = d6[b * 16 + e]; }
  __syncthreads();
  int wave = tid >> 6, lane = tid & 63;
#pragma unroll
  for (int gi = 0; gi < 4; ++gi) {
    int g = wave * 4 + gi;
    float A[36];
#pragma unroll
    for (int l = 0; l < 6; ++l) {
#pragma unroll
      for (int q = 0; q < 6; ++q) A[l * 6 + q] = aff[(l * 32 + 2 * g) * 3 + q];
    }
    float z6 = zrow[4112 + g];
    const uint16_t* prow_g = &prow[g][0];
    float* orow = out + ((size_t)(b * 32 + 2 * g) * 512 + j) * 512;
    const float* z1p = zrow + g * 171;
    const float* z2p = zrow + 2736 + g * 57;
    const float* z3p = zrow + 3648 + g * 19;
    const float* z4p = zrow + 3952 + g * 7;
    const float* z5p = zrow + 4064 + g * 3;
#pragma unroll
    for (int k = 0; k < 4; ++k) {
      int i = (lane << 1) + (k << 7);
      uint32_t pv = *(const uint32_t*)(prow_g + i);
      float pA = bf2f(pv & 0xFFFFu), pB = bf2f(pv >> 16);
      int ib = i + 1;
      float za1 = z1p[(i * 171) >> 9], zb1 = z1p[(ib * 171) >> 9];
      float za2 = z2p[(i * 57) >> 9],  zb2 = z2p[(ib * 57) >> 9];
      float za3 = z3p[(i * 19) >> 9],  zb3 = z3p[(ib * 19) >> 9];
      float za4 = z4p[(i * 7) >> 9],   zb4 = z4p[(ib * 7) >> 9];
      float za5 = z5p[(i * 3) >> 9],   zb5 = z5p[(ib * 3) >> 9];
      float o0a = 0.f, o1a = 0.f, prevA = pA;
      float o0b = 0.f, o1b = 0.f, prevB = pB;
#define ST(L, ZA, ZB) { float y_; \
      y_ = fmaf(A[L*6+0], prevA, fmaf(A[L*6+1], (ZA), A[L*6+2])); o0a += fmaxf(y_, 0.01f * y_); \
      y_ = fmaf(A[L*6+3], prevA, fmaf(A[L*6+4], (ZA), A[L*6+5])); o1a += fmaxf(y_, 0.01f * y_); \
      y_ = fmaf(A[L*6+0], prevB, fmaf(A[L*6+1], (ZB), A[L*6+2])); o0b += fmaxf(y_, 0.01f * y_); \
      y_ = fmaf(A[L*6+3], prevB, fmaf(A[L*6+4], (ZB), A[L*6+5])); o1b += fmaxf(y_, 0.01f * y_); \
      prevA = (ZA); prevB = (ZB); }
      ST(0, za1, zb1) ST(1, za2, zb2) ST(2, za3, zb3) ST(3, za4, zb4) ST(4, za5, zb5) ST(5, z6, z6)
#undef ST
      float2 s0 = make_float2(o0a, o0b);
      float2 s1 = make_float2(o1a, o1b);
      *(float2*)(orow + i) = s0;
      *(float2*)(orow + 262144 + i) = s1;
    }
  }
}

// ---------------------------------------------------------------------------
extern "C" void kernel_launch(void* const* d_in, const int* in_sizes, int n_in,
                              void* d_out, int out_size, void* d_ws, size_t ws_size,
                              hipStream_t stream) {
  const float* x   = (const float*)d_in[0];
  const float* pw1 = (const float*)d_in[1];
  const float* pb1 = (const float*)d_in[2];
  const float* g1  = (const float*)d_in[3];
  const float* be1 = (const float*)d_in[4];
  const float* pw2 = (const float*)d_in[5];
  const float* pb2 = (const float*)d_in[6];
  const float* g2  = (const float*)d_in[7];
  const float* be2 = (const float*)d_in[8];
  const float* dw  = (const float*)d_in[9];
  const float* sw  = (const float*)d_in[10];
  const float* gs  = (const float*)d_in[11];
  const float* bs  = (const float*)d_in[12];
  char* ws = (char*)d_ws;
  float*    stats = (float*)(ws + OFF_STATS);
  uint32_t* hist  = (uint32_t*)(ws + OFF_HIST);
  uint32_t* lut   = (uint32_t*)(ws + OFF_LUT);
  uint8_t*  mode  = (uint8_t*)(ws + OFF_MODE);
  float* d1 = (float*)(ws + OFF_D1);
  float* d2 = (float*)(ws + OFF_D2);
  float* d3 = (float*)(ws + OFF_D3);
  float* d4 = (float*)(ws + OFF_D4);
  float* d5 = (float*)(ws + OFF_D5);
  float* d6 = (float*)(ws + OFF_D6);
  float* out = (float*)d_out;

  hipMemsetAsync(ws, 0, 36864, stream);  // stats + hist
  k_modehist<<<256, 256, 0, stream>>>(x, mode, hist);
  k_build<<<1, 256, 0, stream>>>(hist, pw1, pb1, g1, be1, pw2, pb2, g2, be2, stats, lut);
  k_conv1g<<<8 * 171, 256, 0, stream>>>(mode, lut, d1, dw);
  k_conv2_corr1<<<456 + 512, 256, 0, stream>>>(d1, d2, dw, mode, lut, stats);
  k_conv3_pair<<<152 + 512, 256, 0, stream>>>(d2, d3, dw, d1, stats);
  k_tail8<<<8 + 512, 256, 0, stream>>>(d2, d3, d4, d5, d6, dw, stats);
  k_score<<<4096, 256, 0, stream>>>(mode, lut, d1, d2, d3, d4, d5, d6, stats, sw, gs, bs, out);
}

// Round 7
// 739.253 us; speedup vs baseline: 1.1064x; 1.1064x over previous
//
#include <hip/hip_runtime.h>
#include <stdint.h>

// ---------------------------------------------------------------------------
// ColorHead: quantize -> 11x11 mode pool -> (1x1conv+BN+LReLU)x2 ->
//            6-level stride-3 conv pyramid + nearest upsample + grouped 1x1
//            + per-level train-BN -> accumulated score (8,32,512,512) fp32.
// R8: R5 structure (744us proven). k_modehist regression reverted (181us @
//     1 blk/CU, VALUBusy 45% -> latency-bound). Changes vs R5:
//     - k_mode: 16-row tiles, grid 1536 (6 blk/CU, 24 waves/CU vs 12)
//     - k_build: BN affines + internal moments cached in LDS (kills per-bin
//       global re-reads; 1-block kernel is latency-bound)
// ---------------------------------------------------------------------------

#define NPX   2097152          // 8*512*512
#define NINV  (1.0f/2097152.0f)

// ---- workspace layout (bytes) ----
#define OFF_STATS 0            // float stats[4096]
#define OFF_HIST  16384        // uint32 hist[4913]
#define OFF_LUT   36864        // uint32 lut[4913*8]  (16 bf16 per combo)
#define OFF_MODE  194560       // uint8 mode[8*3*512*512]
#define OFF_D1    73594880     // float d1[8*16*171*171]
#define OFF_D2    88566272     // float d2[8*16*57*57]
#define OFF_D3    90229760     // float d3[8*16*19*19]
#define OFF_D4    90414592     // float d4[8*16*7*7]
#define OFF_D5    90439680     // float d5[8*16*3*3]
#define OFF_D6    90444288     // float d6[8*16*1*1]

// ---- stats region (float indices) ----
#define S_PREP    184   // 16  (+S2 at 200) — consumed by k_score
#define S2_PREP   200   // 16
#define S_Z1      216   // 16  (+S2_Z1 232, S_PZ1 248: 48 contiguous)
#define S2_Z1     232
#define S_PZ1     248
#define S_LVLBASE 264   // levels 2..6: 48 each {Sz,Sz2,Szz}

__device__ __forceinline__ uint32_t f2bf(float f) {
  uint32_t u = __float_as_uint(f);
  u += 0x7FFFu + ((u >> 16) & 1u);
  return u >> 16;
}
__device__ __forceinline__ float bf2f(uint32_t u) {
  return __uint_as_float(u << 16);
}

__device__ __forceinline__ float wave_red(float v) {
  v += __shfl_down(v, 32); v += __shfl_down(v, 16); v += __shfl_down(v, 8);
  v += __shfl_down(v, 4);  v += __shfl_down(v, 2);  v += __shfl_down(v, 1);
  return v;
}

// block = 256 threads. Reduce K per-thread partials, then atomic/store.
template<int K, bool ATOMIC>
__device__ __forceinline__ void block_red(float* acc, float* dst, float* lds) {
  int lane = threadIdx.x & 63, wid = threadIdx.x >> 6;
#pragma unroll
  for (int k = 0; k < K; ++k) {
    float v = wave_red(acc[k]);
    if (lane == 0) lds[wid * K + k] = v;
  }
  __syncthreads();
  if ((int)threadIdx.x < K) {
    float s = lds[threadIdx.x] + lds[K + threadIdx.x] + lds[2 * K + threadIdx.x] + lds[3 * K + threadIdx.x];
    if (ATOMIC) atomicAdd(&dst[threadIdx.x], s);
    else        dst[threadIdx.x] = s;
  }
}

// ---------------------------------------------------------------------------
// K1: quantize + 11x11 reflect-padded mode pool. 16-row tiles for occupancy:
//     grid 1536 = (32 rowblk, 2 colblk, 24 planes) -> 6 blocks/CU, 24 waves/CU.
// ---------------------------------------------------------------------------
__global__ __launch_bounds__(256) void k_mode(const float* __restrict__ x,
                                              uint8_t* __restrict__ mode) {
  int bx = blockIdx.x;
  int rb = bx & 31, cb = (bx >> 5) & 1, pl = bx >> 6;  // 32 rowblk, 2 colblk, 24 planes
  __shared__ uint8_t tile[26][272];
  const float* xp = x + (size_t)pl * 262144;
  int tid = threadIdx.x;
  for (int e = tid; e < 26 * 266; e += 256) {
    int lr = e / 266, lc = e - lr * 266;
    int gr = rb * 16 - 5 + lr; if (gr < 0) gr = -gr; else if (gr > 511) gr = 1022 - gr;
    int gc = cb * 256 - 5 + lc; if (gc < 0) gc = -gc; else if (gc > 511) gc = 1022 - gc;
    float v = xp[gr * 512 + gc];
    tile[lr][lc] = (uint8_t)(int)rintf((v * 255.0f) * 0.0625f);
  }
  __syncthreads();
  int t = tid;
  uint32_t h0 = 0, h1 = 0, h2 = 0, h3 = 0, h4 = 0;
#define ADDV(vv) { int v_ = (vv); uint32_t inc_ = 1u << ((v_ & 3) << 3); int w_ = v_ >> 2; \
    h0 += (w_ == 0) ? inc_ : 0u; h1 += (w_ == 1) ? inc_ : 0u; h2 += (w_ == 2) ? inc_ : 0u; \
    h3 += (w_ == 3) ? inc_ : 0u; h4 += (w_ == 4) ? inc_ : 0u; }
#define SUBV(vv) { int v_ = (vv); uint32_t inc_ = 1u << ((v_ & 3) << 3); int w_ = v_ >> 2; \
    h0 -= (w_ == 0) ? inc_ : 0u; h1 -= (w_ == 1) ? inc_ : 0u; h2 -= (w_ == 2) ? inc_ : 0u; \
    h3 -= (w_ == 3) ? inc_ : 0u; h4 -= (w_ == 4) ? inc_ : 0u; }
#define SCAN_STORE(OI) { uint32_t best_ = h0 & 255u; int bi_ = 0; uint32_t c_; \
    c_ = (h0 >> 8)  & 255u; if (c_ > best_) { best_ = c_; bi_ = 1; } \
    c_ = (h0 >> 16) & 255u; if (c_ > best_) { best_ = c_; bi_ = 2; } \
    c_ = (h0 >> 24);        if (c_ > best_) { best_ = c_; bi_ = 3; } \
    c_ = h1 & 255u;         if (c_ > best_) { best_ = c_; bi_ = 4; } \
    c_ = (h1 >> 8)  & 255u; if (c_ > best_) { best_ = c_; bi_ = 5; } \
    c_ = (h1 >> 16) & 255u; if (c_ > best_) { best_ = c_; bi_ = 6; } \
    c_ = (h1 >> 24);        if (c_ > best_) { best_ = c_; bi_ = 7; } \
    c_ = h2 & 255u;         if (c_ > best_) { best_ = c_; bi_ = 8; } \
    c_ = (h2 >> 8)  & 255u; if (c_ > best_) { best_ = c_; bi_ = 9; } \
    c_ = (h2 >> 16) & 255u; if (c_ > best_) { best_ = c_; bi_ = 10; } \
    c_ = (h2 >> 24);        if (c_ > best_) { best_ = c_; bi_ = 11; } \
    c_ = h3 & 255u;         if (c_ > best_) { best_ = c_; bi_ = 12; } \
    c_ = (h3 >> 8)  & 255u; if (c_ > best_) { best_ = c_; bi_ = 13; } \
    c_ = (h3 >> 16) & 255u; if (c_ > best_) { best_ = c_; bi_ = 14; } \
    c_ = (h3 >> 24);        if (c_ > best_) { best_ = c_; bi_ = 15; } \
    c_ = h4 & 255u;         if (c_ > best_) { best_ = c_; bi_ = 16; } \
    mode[OI] = (uint8_t)bi_; }
#pragma unroll
  for (int dy = 0; dy < 11; ++dy) {
#pragma unroll
    for (int dx = 0; dx < 11; ++dx) ADDV(tile[dy][t + dx]);
  }
  size_t ob = (size_t)pl * 262144 + (size_t)(rb * 16) * 512 + cb * 256 + t;
  SCAN_STORE(ob);
  for (int s = 1; s < 16; ++s) {
#pragma unroll
    for (int dx = 0; dx < 11; ++dx) { SUBV(tile[s - 1][t + dx]); ADDV(tile[s + 10][t + dx]); }
    SCAN_STORE(ob + (size_t)s * 512);
  }
#undef ADDV
#undef SUBV
#undef SCAN_STORE
}

// ---------------------------------------------------------------------------
// K2: histogram of 3-channel mode combos (17^3 = 4913 bins). grid 256.
// ---------------------------------------------------------------------------
__global__ __launch_bounds__(256) void k_hist(const uint8_t* __restrict__ mode,
                                              uint32_t* __restrict__ hist) {
  __shared__ uint32_t h[4913];
  int tid = threadIdx.x;
  for (int e = tid; e < 4913; e += 256) h[e] = 0;
  __syncthreads();
  int base = blockIdx.x * 8192;
  for (int it = 0; it < 16; ++it) {
    int px = base + it * 512 + tid * 2;
    int b = px >> 18, rem = px & 262143;
    const uint8_t* mp = mode + (size_t)b * 786432 + rem;
    uint32_t m0 = *(const uint16_t*)(mp);
    uint32_t m1 = *(const uint16_t*)(mp + 262144);
    uint32_t m2 = *(const uint16_t*)(mp + 524288);
    int c0 = (int)(m0 & 255u) + 17 * (int)(m1 & 255u) + 289 * (int)(m2 & 255u);
    int c1 = (int)(m0 >> 8)   + 17 * (int)(m1 >> 8)   + 289 * (int)(m2 >> 8);
    atomicAdd(&h[c0], 1u);
    atomicAdd(&h[c1], 1u);
  }
  __syncthreads();
  for (int e = tid; e < 4913; e += 256)
    if (h[e]) atomicAdd(&hist[e], h[e]);
}

// ---------------------------------------------------------------------------
// K3: one-block build: pre1 moments -> BN1 -> h1 moments -> BN2 -> LUT + prep
//     moments. All intermediates in LDS (1-block kernel is latency-bound;
//     per-bin global re-reads of affines were unhidden latency).
// ---------------------------------------------------------------------------
__global__ __launch_bounds__(256) void k_build(const uint32_t* __restrict__ hist,
    const float* __restrict__ pw1, const float* __restrict__ pb1,
    const float* __restrict__ g1,  const float* __restrict__ be1,
    const float* __restrict__ pw2, const float* __restrict__ pb2,
    const float* __restrict__ g2,  const float* __restrict__ be2,
    float* __restrict__ stats, uint32_t* __restrict__ lut) {
  __shared__ float red[4 * 152];
  __shared__ float sW1[48], sP1[16];     // pw1, pb1
  __shared__ float sA1[48], sB1[16];     // BN1 affine
  __shared__ float sA2[256], sB2[16];    // BN2 affine
  __shared__ float sPre[32], sH[152];    // internal moments
  int tid = threadIdx.x;
  if (tid < 48) sW1[tid] = pw1[tid];
  if (tid < 16) sP1[tid] = pb1[tid];
  __syncthreads();
  // ---- phase A: pre1 = pw1*xq + pb1 moments ----
  {
    float acc[32];
#pragma unroll
    for (int k = 0; k < 32; ++k) acc[k] = 0.f;
    for (int bin = tid; bin < 4913; bin += 256) {
      float w = (float)hist[bin];
      if (w == 0.f) continue;
      int m0 = bin % 17, r = bin / 17;
      int m1 = r % 17, m2 = r / 17;
      float x0 = m0 * 0.0625f, x1 = m1 * 0.0625f, x2 = m2 * 0.0625f;
#pragma unroll
      for (int o = 0; o < 16; ++o) {
        float p = fmaf(sW1[o * 3], x0, fmaf(sW1[o * 3 + 1], x1, fmaf(sW1[o * 3 + 2], x2, sP1[o])));
        acc[o] = fmaf(w, p, acc[o]);
        acc[16 + o] = fmaf(w * p, p, acc[16 + o]);
      }
    }
    block_red<32, false>(acc, sPre, red);
  }
  __syncthreads();
  if (tid < 16) {  // BN1 affine
    int o = tid;
    float m = sPre[o] * NINV;
    float var = sPre[16 + o] * NINV - m * m;
    float s = g1[o] * rsqrtf(var + 1e-5f);
    sA1[o * 3 + 0] = sW1[o * 3 + 0] * s;
    sA1[o * 3 + 1] = sW1[o * 3 + 1] * s;
    sA1[o * 3 + 2] = sW1[o * 3 + 2] * s;
    sB1[o] = (sP1[o] - m) * s + be1[o];
  }
  __syncthreads();
  // ---- phase B: h1 moments (16 sums + 136 upper-tri) ----
  {
    float acc[152];
#pragma unroll
    for (int k = 0; k < 152; ++k) acc[k] = 0.f;
    for (int bin = tid; bin < 4913; bin += 256) {
      float w = (float)hist[bin];
      if (w == 0.f) continue;
      int m0 = bin % 17, r = bin / 17;
      int m1 = r % 17, m2 = r / 17;
      float x0 = m0 * 0.0625f, x1 = m1 * 0.0625f, x2 = m2 * 0.0625f;
      float h[16];
#pragma unroll
      for (int c = 0; c < 16; ++c) {
        float y = fmaf(sA1[c * 3], x0, fmaf(sA1[c * 3 + 1], x1,
                  fmaf(sA1[c * 3 + 2], x2, sB1[c])));
        h[c] = fmaxf(y, 0.01f * y);
        acc[c] = fmaf(w, h[c], acc[c]);
      }
#pragma unroll
      for (int c = 0; c < 16; ++c) {
#pragma unroll
        for (int c2 = c; c2 < 16; ++c2) {
          int idx = 16 * c - (c * (c - 1)) / 2 + (c2 - c);
          acc[16 + idx] = fmaf(w * h[c], h[c2], acc[16 + idx]);
        }
      }
    }
    block_red<152, false>(acc, sH, red);
  }
  __syncthreads();
  if (tid < 16) {  // BN2 affine
    int o = tid;
    float s1 = 0.f;
#pragma unroll
    for (int c = 0; c < 16; ++c) s1 = fmaf(pw2[o * 16 + c], sH[c] * NINV, s1);
    float e2 = 0.f;
#pragma unroll
    for (int c = 0; c < 16; ++c) {
#pragma unroll
      for (int c2 = 0; c2 < 16; ++c2) {
        int lo = c < c2 ? c : c2, hi = c < c2 ? c2 : c;
        int idx = 16 * lo - (lo * (lo - 1)) / 2 + (hi - lo);
        e2 = fmaf(pw2[o * 16 + c] * pw2[o * 16 + c2], sH[16 + idx] * NINV, e2);
      }
    }
    float var = e2 - s1 * s1;
    float mean = s1 + pb2[o];
    float s = g2[o] * rsqrtf(var + 1e-5f);
#pragma unroll
    for (int c = 0; c < 16; ++c) sA2[o * 16 + c] = pw2[o * 16 + c] * s;
    sB2[o] = (pb2[o] - mean) * s + be2[o];
  }
  __syncthreads();
  // ---- phase C: LUT (bf16-packed prep per combo) + prep moments ----
  {
    float acc[32];
#pragma unroll
    for (int k = 0; k < 32; ++k) acc[k] = 0.f;
    for (int bin = tid; bin < 4913; bin += 256) {
      float w = (float)hist[bin];
      int m0 = bin % 17, r = bin / 17;
      int m1 = r % 17, m2 = r / 17;
      float x0 = m0 * 0.0625f, x1 = m1 * 0.0625f, x2 = m2 * 0.0625f;
      float h[16];
#pragma unroll
      for (int c = 0; c < 16; ++c) {
        float y = fmaf(sA1[c * 3], x0, fmaf(sA1[c * 3 + 1], x1,
                  fmaf(sA1[c * 3 + 2], x2, sB1[c])));
        h[c] = fmaxf(y, 0.01f * y);
      }
      float p[16];
#pragma unroll
      for (int o = 0; o < 16; ++o) {
        float y = sB2[o];
#pragma unroll
        for (int c = 0; c < 16; ++c) y = fmaf(sA2[o * 16 + c], h[c], y);
        p[o] = fmaxf(y, 0.01f * y);
        acc[o] = fmaf(w, p[o], acc[o]);
        acc[16 + o] = fmaf(w * p[o], p[o], acc[16 + o]);
      }
#pragma unroll
      for (int d = 0; d < 8; ++d)
        lut[bin * 8 + d] = f2bf(p[2 * d]) | (f2bf(p[2 * d + 1]) << 16);
    }
    block_red<32, false>(acc, stats + S_PREP, red);
  }
}

// ---------------------------------------------------------------------------
// conv body: 3x3 stride 3 pad 1, 16->16 channels, fp32 in/out.
// ---------------------------------------------------------------------------
template<int HIN, int WIN, int HOUT, int WOUT>
__device__ __forceinline__ void conv_body(const float* __restrict__ in,
                                          float* __restrict__ out,
                                          const float* __restrict__ dw, int bx) {
  __shared__ float tile[3][16][WIN + 2];
  int r = bx % HOUT, b = bx / HOUT;
  int tid = threadIdx.x;
  for (int e = tid; e < 48; e += 256) { tile[e / 16][e & 15][0] = 0.f; tile[e / 16][e & 15][WIN + 1] = 0.f; }
  for (int e = tid; e < 3 * 16 * WIN; e += 256) {
    int ky = e / (16 * WIN); int rem = e - ky * (16 * WIN); int ic = rem / WIN; int col = rem - ic * WIN;
    int gr = 3 * r - 1 + ky;
    float v = 0.f;
    if (gr >= 0 && gr < HIN) v = in[((size_t)(b * 16 + ic) * HIN + gr) * WIN + col];
    tile[ky][ic][col + 1] = v;
  }
  __syncthreads();
  int c = tid;
  if (c < WOUT) {
    float acc[16];
#pragma unroll
    for (int o = 0; o < 16; ++o) acc[o] = 0.f;
#pragma unroll
    for (int ic = 0; ic < 16; ++ic) {
      float v[9];
#pragma unroll
      for (int ky = 0; ky < 3; ++ky) {
#pragma unroll
        for (int kx = 0; kx < 3; ++kx) v[ky * 3 + kx] = tile[ky][ic][3 * c + kx];
      }
#pragma unroll
      for (int o = 0; o < 16; ++o) {
        const float* w = dw + (o * 16 + ic) * 9;
#pragma unroll
        for (int tp = 0; tp < 9; ++tp) acc[o] = fmaf(v[tp], w[tp], acc[o]);
      }
    }
#pragma unroll
    for (int o = 0; o < 16; ++o)
      out[((size_t)(b * 16 + o) * HOUT + r) * WOUT + c] = acc[o];
  }
}

// pair stats body: Sz, Sz^2, S(z_{l-1} z_l) over dst grid. 512 blocks' worth.
template<int HP, int HZ>
__device__ __forceinline__ void pair_body(const float* __restrict__ dp,
                                          const float* __restrict__ dz,
                                          float* __restrict__ dst, int bx) {
  int g = bx & 15, b = (bx >> 4) & 7, jq = bx >> 7;
  const float* dpp = dp + (size_t)(b * 16 + g) * HP * HP;
  const float* dzp = dz + (size_t)(b * 16 + g) * HZ * HZ;
  float a1 = 0.f, a2 = 0.f, a3 = 0.f;
  for (int j = jq * 128; j < jq * 128 + 128; ++j) {
    int r1 = (j * HP) >> 9, r2 = (j * HZ) >> 9;
    const float* rp = dpp + r1 * HP;
    const float* rz = dzp + r2 * HZ;
    for (int i = threadIdx.x; i < 512; i += 256) {
      int c1 = (i * HP) >> 9, c2 = (i * HZ) >> 9;
      float zp = rp[c1], zz = rz[c2];
      a1 += zz; a2 = fmaf(zz, zz, a2); a3 = fmaf(zp, zz, a3);
    }
  }
  a1 = wave_red(a1); a2 = wave_red(a2); a3 = wave_red(a3);
  __shared__ float red[12];
  int lane = threadIdx.x & 63, wid = threadIdx.x >> 6;
  if (!lane) { red[wid * 3] = a1; red[wid * 3 + 1] = a2; red[wid * 3 + 2] = a3; }
  __syncthreads();
  if (threadIdx.x < 3) {
    float s = red[threadIdx.x] + red[3 + threadIdx.x] + red[6 + threadIdx.x] + red[9 + threadIdx.x];
    atomicAdd(&dst[threadIdx.x * 16 + g], s);
  }
}

// level-1 stats body: Sz1, Sz1^2, S(prep*z1); prep gathered from mode+LUT.
__device__ __forceinline__ void corr1_body(const uint8_t* __restrict__ mode,
                                           const uint32_t* __restrict__ lut,
                                           const float* __restrict__ d1,
                                           float* __restrict__ stats, int bx) {
  int b = bx >> 6, band = bx & 63;
  float acc[48];
#pragma unroll
  for (int k = 0; k < 48; ++k) acc[k] = 0.f;
  for (int jj = 0; jj < 8; ++jj) {
    int j = band * 8 + jj;
    int r1 = (j * 171) >> 9;
#pragma unroll
    for (int ii = 0; ii < 2; ++ii) {
      int i = (int)threadIdx.x + ii * 256;
      int c1 = (i * 171) >> 9;
      const uint8_t* mp = mode + (size_t)b * 786432 + j * 512 + i;
      int combo = (int)mp[0] + 17 * (int)mp[262144] + 289 * (int)mp[524288];
      const uint4* L = (const uint4*)(lut + combo * 8);
      uint4 q0 = L[0], q1 = L[1];
      uint32_t q[8] = {q0.x, q0.y, q0.z, q0.w, q1.x, q1.y, q1.z, q1.w};
#pragma unroll
      for (int g = 0; g < 16; ++g) {
        float p = bf2f((g & 1) ? (q[g >> 1] >> 16) : (q[g >> 1] & 0xFFFFu));
        float z = d1[((size_t)(b * 16 + g) * 171 + r1) * 171 + c1];
        acc[g] += z; acc[16 + g] = fmaf(z, z, acc[16 + g]); acc[32 + g] = fmaf(p, z, acc[32 + g]);
      }
    }
  }
  __shared__ float red[4 * 48];
  block_red<48, true>(acc, stats + S_Z1, red);
}

// ---------------------------------------------------------------------------
// K4: level-1 conv, input gathered from mode+LUT (bf16 LUT lines, L2-resident).
// ---------------------------------------------------------------------------
__global__ __launch_bounds__(256) void k_conv1g(const uint8_t* __restrict__ mode,
                                                const uint32_t* __restrict__ lut,
                                                float* __restrict__ out,
                                                const float* __restrict__ dw) {
  __shared__ uint16_t tile[3][16][514];
  int bx = blockIdx.x; int r = bx % 171, b = bx / 171;
  int tid = threadIdx.x;
  for (int e = tid; e < 48; e += 256) { tile[e / 16][e & 15][0] = 0; tile[e / 16][e & 15][513] = 0; }
  for (int e = tid; e < 3 * 512; e += 256) {
    int ky = e >> 9, col = e & 511;
    int gr = 3 * r - 1 + ky;
    if (gr < 0 || gr > 511) {
#pragma unroll
      for (int c = 0; c < 16; ++c) tile[ky][c][col + 1] = 0;
    } else {
      const uint8_t* mp = mode + (size_t)b * 786432 + gr * 512 + col;
      int combo = (int)mp[0] + 17 * (int)mp[262144] + 289 * (int)mp[524288];
      const uint4* L = (const uint4*)(lut + combo * 8);
      uint4 q0 = L[0], q1 = L[1];
      uint32_t q[8] = {q0.x, q0.y, q0.z, q0.w, q1.x, q1.y, q1.z, q1.w};
#pragma unroll
      for (int d = 0; d < 8; ++d) {
        tile[ky][2 * d][col + 1]     = (uint16_t)(q[d] & 0xFFFFu);
        tile[ky][2 * d + 1][col + 1] = (uint16_t)(q[d] >> 16);
      }
    }
  }
  __syncthreads();
  int c = tid;
  if (c < 171) {
    float acc[16];
#pragma unroll
    for (int o = 0; o < 16; ++o) acc[o] = 0.f;
#pragma unroll
    for (int ic = 0; ic < 16; ++ic) {
      float v[9];
#pragma unroll
      for (int ky = 0; ky < 3; ++ky) {
#pragma unroll
        for (int kx = 0; kx < 3; ++kx)
          v[ky * 3 + kx] = __uint_as_float(((uint32_t)tile[ky][ic][3 * c + kx]) << 16);
      }
#pragma unroll
      for (int o = 0; o < 16; ++o) {
        const float* w = dw + (o * 16 + ic) * 9;
#pragma unroll
        for (int tp = 0; tp < 9; ++tp) acc[o] = fmaf(v[tp], w[tp], acc[o]);
      }
    }
#pragma unroll
    for (int o = 0; o < 16; ++o)
      out[((size_t)(b * 16 + o) * 171 + r) * 171 + c] = acc[o];
  }
}

// K5: conv level 2 (456 blocks) + corr1 stats (512 blocks) in one dispatch.
__global__ __launch_bounds__(256) void k_conv2_corr1(const float* __restrict__ d1,
    float* __restrict__ d2, const float* __restrict__ dw,
    const uint8_t* __restrict__ mode, const uint32_t* __restrict__ lut,
    float* __restrict__ stats) {
  if ((int)blockIdx.x < 456) conv_body<171, 171, 57, 57>(d1, d2, dw, (int)blockIdx.x);
  else                       corr1_body(mode, lut, d1, stats, (int)blockIdx.x - 456);
}

// K6: conv level 3 (152 blocks) + pair stats for level 2 (512 blocks).
__global__ __launch_bounds__(256) void k_conv3_pair(const float* __restrict__ d2,
    float* __restrict__ d3, const float* __restrict__ dw,
    const float* __restrict__ d1, float* __restrict__ stats) {
  if ((int)blockIdx.x < 152) conv_body<57, 57, 19, 19>(d2, d3, dw, (int)blockIdx.x);
  else                       pair_body<171, 57>(d1, d2, stats + S_LVLBASE, (int)blockIdx.x - 152);
}

// ---------------------------------------------------------------------------
// K7: k_tail8: blocks 0..7 = per-batch {conv4, pair4-exact, conv5, pair5-exact,
//     conv6, pair6-closed} with dw cached in LDS; blocks 8..519 = pair<57,19>
//     rider for level-3 stats.
// ---------------------------------------------------------------------------
__global__ __launch_bounds__(256) void k_tail8(const float* __restrict__ d2,
    const float* __restrict__ d3, float* __restrict__ d4, float* __restrict__ d5,
    float* __restrict__ d6, const float* __restrict__ dw, float* __restrict__ stats) {
  int bx = blockIdx.x;
  if (bx >= 8) { pair_body<57, 19>(d2, d3, stats + S_LVLBASE + 48, bx - 8); return; }
  __shared__ float s3[16][19][19];
  __shared__ float s4[16][7][7];
  __shared__ float s5[16][3][3];
  __shared__ float s6[16];
  __shared__ float dwS[2304];
  __shared__ float acc[144];   // {Sz4,Sz4²,Sz3z4}[48] {z5..}[48] {z6..}[48]
  int tid = threadIdx.x, b = bx;
  for (int e = tid; e < 2304; e += 256) dwS[e] = dw[e];
  for (int e = tid; e < 144; e += 256) acc[e] = 0.f;
  for (int e = tid; e < 16 * 361; e += 256) ((float*)s3)[e] = d3[(size_t)b * 5776 + e];
  __syncthreads();
  // conv4: d3(19) -> d4(7)
  for (int e = tid; e < 784; e += 256) {
    int o = e / 49, rc = e - o * 49; int r = rc / 7, c = rc % 7;
    float a = 0.f;
#pragma unroll
    for (int ic = 0; ic < 16; ++ic) {
      const float* w = dwS + (o * 16 + ic) * 9;
#pragma unroll
      for (int ky = 0; ky < 3; ++ky) {
        int gr = 3 * r - 1 + ky; if (gr < 0 || gr > 18) continue;
#pragma unroll
        for (int kx = 0; kx < 3; ++kx) {
          int gc = 3 * c - 1 + kx; if (gc < 0 || gc > 18) continue;
          a = fmaf(s3[ic][gr][gc], w[ky * 3 + kx], a);
        }
      }
    }
    s4[o][r][c] = a; d4[((size_t)(b * 16 + o) * 7 + r) * 7 + c] = a;
  }
  __syncthreads();
  // pair4 (19 -> 7) exact counts ; conv5: s4 -> s5, d5
  for (int e = tid; e < 784; e += 256) {
    int g = e & 15, rc = e >> 4; int r2 = rc / 7, c2 = rc % 7;
    int loZ = (512 * r2 + 6) / 7, hiZ = (512 * (r2 + 1) + 6) / 7;
    int loC = (512 * c2 + 6) / 7, hiC = (512 * (c2 + 1) + 6) / 7;
    int rrmin = (loZ * 19) >> 9, rrmax = ((hiZ - 1) * 19) >> 9;
    int ccmin = (loC * 19) >> 9, ccmax = ((hiC - 1) * 19) >> 9;
    float z = s4[g][r2][c2];
    float B = 0.f;
    for (int rr = rrmin; rr <= rrmax; ++rr) {
      int loP = (512 * rr + 18) / 19, hiP = (512 * (rr + 1) + 18) / 19;
      int cntR = min(hiP, hiZ) - max(loP, loZ); if (cntR <= 0) continue;
      float rowS = 0.f;
      for (int cc = ccmin; cc <= ccmax; ++cc) {
        int loQ = (512 * cc + 18) / 19, hiQ = (512 * (cc + 1) + 18) / 19;
        int cntC = min(hiQ, hiC) - max(loQ, loC); if (cntC <= 0) continue;
        rowS = fmaf((float)cntC, s3[g][rr][cc], rowS);
      }
      B = fmaf((float)cntR, rowS, B);
    }
    float wgt = (float)((hiZ - loZ) * (hiC - loC));
    atomicAdd(&acc[g], wgt * z);
    atomicAdd(&acc[16 + g], wgt * z * z);
    atomicAdd(&acc[32 + g], B * z);
  }
  for (int e = tid; e < 144; e += 256) {
    int o = e / 9, rc = e - o * 9; int r = rc / 3, c = rc % 3;
    float a = 0.f;
#pragma unroll
    for (int ic = 0; ic < 16; ++ic) {
      const float* w = dwS + (o * 16 + ic) * 9;
#pragma unroll
      for (int ky = 0; ky < 3; ++ky) {
        int gr = 3 * r - 1 + ky; if (gr < 0 || gr > 6) continue;
#pragma unroll
        for (int kx = 0; kx < 3; ++kx) {
          int gc = 3 * c - 1 + kx; if (gc < 0 || gc > 6) continue;
          a = fmaf(s4[ic][gr][gc], w[ky * 3 + kx], a);
        }
      }
    }
    s5[o][r][c] = a; d5[((size_t)(b * 16 + o) * 3 + r) * 3 + c] = a;
  }
  __syncthreads();
  // pair5 (7 -> 3) exact counts ; conv6: s5 -> s6, d6
  for (int e = tid; e < 144; e += 256) {
    int g = e & 15, rc = e >> 4; int r2 = rc / 3, c2 = rc % 3;
    int loZ = (512 * r2 + 2) / 3, hiZ = (512 * (r2 + 1) + 2) / 3;
    int loC = (512 * c2 + 2) / 3, hiC = (512 * (c2 + 1) + 2) / 3;
    int rrmin = (loZ * 7) >> 9, rrmax = ((hiZ - 1) * 7) >> 9;
    int ccmin = (loC * 7) >> 9, ccmax = ((hiC - 1) * 7) >> 9;
    float z = s5[g][r2][c2];
    float B = 0.f;
    for (int rr = rrmin; rr <= rrmax; ++rr) {
      int loP = (512 * rr + 6) / 7, hiP = (512 * (rr + 1) + 6) / 7;
      int cntR = min(hiP, hiZ) - max(loP, loZ); if (cntR <= 0) continue;
      float rowS = 0.f;
      for (int cc = ccmin; cc <= ccmax; ++cc) {
        int loQ = (512 * cc + 6) / 7, hiQ = (512 * (cc + 1) + 6) / 7;
        int cntC = min(hiQ, hiC) - max(loQ, loC); if (cntC <= 0) continue;
        rowS = fmaf((float)cntC, s4[g][rr][cc], rowS);
      }
      B = fmaf((float)cntR, rowS, B);
    }
    float wgt = (float)((hiZ - loZ) * (hiC - loC));
    atomicAdd(&acc[48 + g], wgt * z);
    atomicAdd(&acc[64 + g], wgt * z * z);
    atomicAdd(&acc[80 + g], B * z);
  }
  if (tid < 16) {
    int o = tid; float a = 0.f;
#pragma unroll
    for (int ic = 0; ic < 16; ++ic) {
      const float* w = dwS + (o * 16 + ic) * 9;
#pragma unroll
      for (int ky = 1; ky < 3; ++ky)
#pragma unroll
        for (int kx = 1; kx < 3; ++kx)
          a = fmaf(s5[ic][ky - 1][kx - 1], w[ky * 3 + kx], a);
    }
    s6[o] = a; d6[b * 16 + o] = a;
  }
  __syncthreads();
  // pair6 (3 -> 1) closed form: z6 constant; nearest weights 171/171/170
  if (tid < 16) {
    int g = tid; float z6 = s6[g];
    const float wr3[3] = {171.f, 171.f, 170.f};
    float s5s = 0.f;
#pragma unroll
    for (int r = 0; r < 3; ++r)
#pragma unroll
      for (int c = 0; c < 3; ++c) s5s = fmaf(wr3[r] * wr3[c], s5[g][r][c], s5s);
    acc[96 + g]  += 262144.f * z6;
    acc[112 + g] += 262144.f * z6 * z6;
    acc[128 + g] += z6 * s5s;
  }
  __syncthreads();
  for (int e = tid; e < 144; e += 256)
    atomicAdd(&stats[S_LVLBASE + 96 + e], acc[e]);
}

// ---------------------------------------------------------------------------
// K8: fused score: BN affines computed in-block from raw sums, then all 6
//     levels in one pass. grid 4096 = (b, row j).
// ---------------------------------------------------------------------------
__global__ __launch_bounds__(256) void k_score(const uint8_t* __restrict__ mode,
    const uint32_t* __restrict__ lut,
    const float* __restrict__ d1, const float* __restrict__ d2, const float* __restrict__ d3,
    const float* __restrict__ d4, const float* __restrict__ d5, const float* __restrict__ d6,
    const float* __restrict__ stats, const float* __restrict__ sw,
    const float* __restrict__ gs, const float* __restrict__ bs,
    float* __restrict__ out) {
  __shared__ float zrow[4128];
  __shared__ float aff[576];
  __shared__ uint16_t prow[16][512];
  int bx = blockIdx.x; int b = bx >> 9, j = bx & 511;
  int tid = threadIdx.x;
  // BN affines from raw sums (~25 flops/thread, redundant per block but free)
  if (tid < 192) {
    int lvl = tid >> 5, ch = tid & 31, g = ch >> 1, o = ch & 1;
    float Sp, Sp2, Sz, Sz2, Spz;
    if (lvl == 0) {
      Sp = stats[S_PREP + g]; Sp2 = stats[S2_PREP + g];
      Sz = stats[S_Z1 + g];   Sz2 = stats[S2_Z1 + g]; Spz = stats[S_PZ1 + g];
    } else {
      int base = S_LVLBASE + (lvl - 1) * 48;
      Sz = stats[base + g]; Sz2 = stats[base + 16 + g]; Spz = stats[base + 32 + g];
      if (lvl == 1) { Sp = stats[S_Z1 + g]; Sp2 = stats[S2_Z1 + g]; }
      else { int pb = S_LVLBASE + (lvl - 2) * 48; Sp = stats[pb + g]; Sp2 = stats[pb + 16 + g]; }
    }
    float mp = Sp * NINV, mz = Sz * NINV;
    float ep2 = Sp2 * NINV, ez2 = Sz2 * NINV, epz = Spz * NINV;
    float w0 = sw[g * 4 + o * 2], w1 = sw[g * 4 + o * 2 + 1];
    float mean = w0 * mp + w1 * mz;
    float e2 = w0 * w0 * ep2 + 2.f * w0 * w1 * epz + w1 * w1 * ez2;
    float var = e2 - mean * mean;
    float s = gs[ch] * rsqrtf(var + 1e-5f);
    aff[(lvl * 32 + ch) * 3 + 0] = s * w0;
    aff[(lvl * 32 + ch) * 3 + 1] = s * w1;
    aff[(lvl * 32 + ch) * 3 + 2] = bs[ch] - mean * s;
  }
  {
    const uint8_t* mp = mode + (size_t)b * 786432 + j * 512 + tid * 2;
    uint32_t m0 = *(const uint16_t*)(mp);
    uint32_t m1 = *(const uint16_t*)(mp + 262144);
    uint32_t m2 = *(const uint16_t*)(mp + 524288);
    int ca = (int)(m0 & 255u) + 17 * (int)(m1 & 255u) + 289 * (int)(m2 & 255u);
    int cb = (int)(m0 >> 8)   + 17 * (int)(m1 >> 8)   + 289 * (int)(m2 >> 8);
    const uint4* La = (const uint4*)(lut + ca * 8);
    const uint4* Lb = (const uint4*)(lut + cb * 8);
    uint4 a0 = La[0], a1 = La[1], b0 = Lb[0], b1 = Lb[1];
    uint32_t pa[8] = {a0.x, a0.y, a0.z, a0.w, a1.x, a1.y, a1.z, a1.w};
    uint32_t pb[8] = {b0.x, b0.y, b0.z, b0.w, b1.x, b1.y, b1.z, b1.w};
    uint32_t* pr32 = (uint32_t*)prow;
#pragma unroll
    for (int c = 0; c < 16; ++c) {
      uint32_t lo = (c & 1) ? (pa[c >> 1] >> 16)         : (pa[c >> 1] & 0xFFFFu);
      uint32_t hi = (c & 1) ? (pb[c >> 1] & 0xFFFF0000u) : (pb[c >> 1] << 16);
      pr32[c * 256 + tid] = lo | hi;
    }
  }
  { int r = (j * 171) >> 9; for (int e = tid; e < 16 * 171; e += 256) { int g = e / 171, c = e - g * 171; zrow[e]        = d1[((size_t)(b * 16 + g) * 171 + r) * 171 + c]; } }
  { int r = (j * 57)  >> 9; for (int e = tid; e < 16 * 57;  e += 256) { int g = e / 57,  c = e - g * 57;  zrow[2736 + e] = d2[((size_t)(b * 16 + g) * 57  + r) * 57  + c]; } }
  { int r = (j * 19)  >> 9; for (int e = tid; e < 16 * 19;  e += 256) { int g = e / 19,  c = e - g * 19;  zrow[3648 + e] = d3[((size_t)(b * 16 + g) * 19  + r) * 19  + c]; } }
  { int r = (j * 7)   >> 9; for (int e = tid; e < 16 * 7;   e += 256) { int g = e / 7,   c = e - g * 7;   zrow[3952 + e] = d4[((size_t)(b * 16 + g) * 7   + r) * 7   + c]; } }
  { int r = (j * 3)   >> 9; for (int e = tid; e < 16 * 3;   e += 256) { int g = e / 3,   c = e - g * 3;   zrow[4064 + e] = d5[((size_t)(b * 16 + g) * 3   + r) * 3   + c]; } }
  { for (int e = tid; e < 16; e += 256) zrow[4112 + e] = d6[b * 16 + e]; }
  __syncthreads();
  int wave = tid >> 6, lane = tid & 63;
#pragma unroll
  for (int gi = 0; gi < 4; ++gi) {
    int g = wave * 4 + gi;
    float A[36];
#pragma unroll
    for (int l = 0; l < 6; ++l) {
#pragma unroll
      for (int q = 0; q < 6; ++q) A[l * 6 + q] = aff[(l * 32 + 2 * g) * 3 + q];
    }
    float z6 = zrow[4112 + g];
    const uint16_t* prow_g = &prow[g][0];
    float* orow = out + ((size_t)(b * 32 + 2 * g) * 512 + j) * 512;
    const float* z1p = zrow + g * 171;
    const float* z2p = zrow + 2736 + g * 57;
    const float* z3p = zrow + 3648 + g * 19;
    const float* z4p = zrow + 3952 + g * 7;
    const float* z5p = zrow + 4064 + g * 3;
#pragma unroll
    for (int k = 0; k < 4; ++k) {
      int i = (lane << 1) + (k << 7);
      uint32_t pv = *(const uint32_t*)(prow_g + i);
      float pA = bf2f(pv & 0xFFFFu), pB = bf2f(pv >> 16);
      int ib = i + 1;
      float za1 = z1p[(i * 171) >> 9], zb1 = z1p[(ib * 171) >> 9];
      float za2 = z2p[(i * 57) >> 9],  zb2 = z2p[(ib * 57) >> 9];
      float za3 = z3p[(i * 19) >> 9],  zb3 = z3p[(ib * 19) >> 9];
      float za4 = z4p[(i * 7) >> 9],   zb4 = z4p[(ib * 7) >> 9];
      float za5 = z5p[(i * 3) >> 9],   zb5 = z5p[(ib * 3) >> 9];
      float o0a = 0.f, o1a = 0.f, prevA = pA;
      float o0b = 0.f, o1b = 0.f, prevB = pB;
#define ST(L, ZA, ZB) { float y_; \
      y_ = fmaf(A[L*6+0], prevA, fmaf(A[L*6+1], (ZA), A[L*6+2])); o0a += fmaxf(y_, 0.01f * y_); \
      y_ = fmaf(A[L*6+3], prevA, fmaf(A[L*6+4], (ZA), A[L*6+5])); o1a += fmaxf(y_, 0.01f * y_); \
      y_ = fmaf(A[L*6+0], prevB, fmaf(A[L*6+1], (ZB), A[L*6+2])); o0b += fmaxf(y_, 0.01f * y_); \
      y_ = fmaf(A[L*6+3], prevB, fmaf(A[L*6+4], (ZB), A[L*6+5])); o1b += fmaxf(y_, 0.01f * y_); \
      prevA = (ZA); prevB = (ZB); }
      ST(0, za1, zb1) ST(1, za2, zb2) ST(2, za3, zb3) ST(3, za4, zb4) ST(4, za5, zb5) ST(5, z6, z6)
#undef ST
      float2 s0 = make_float2(o0a, o0b);
      float2 s1 = make_float2(o1a, o1b);
      *(float2*)(orow + i) = s0;
      *(float2*)(orow + 262144 + i) = s1;
    }
  }
}

// ---------------------------------------------------------------------------
extern "C" void kernel_launch(void* const* d_in, const int* in_sizes, int n_in,
                              void* d_out, int out_size, void* d_ws, size_t ws_size,
                              hipStream_t stream) {
  const float* x   = (const float*)d_in[0];
  const float* pw1 = (const float*)d_in[1];
  const float* pb1 = (const float*)d_in[2];
  const float* g1  = (const float*)d_in[3];
  const float* be1 = (const float*)d_in[4];
  const float* pw2 = (const float*)d_in[5];
  const float* pb2 = (const float*)d_in[6];
  const float* g2  = (const float*)d_in[7];
  const float* be2 = (const float*)d_in[8];
  const float* dw  = (const float*)d_in[9];
  const float* sw  = (const float*)d_in[10];
  const float* gs  = (const float*)d_in[11];
  const float* bs  = (const float*)d_in[12];
  char* ws = (char*)d_ws;
  float*    stats = (float*)(ws + OFF_STATS);
  uint32_t* hist  = (uint32_t*)(ws + OFF_HIST);
  uint32_t* lut   = (uint32_t*)(ws + OFF_LUT);
  uint8_t*  mode  = (uint8_t*)(ws + OFF_MODE);
  float* d1 = (float*)(ws + OFF_D1);
  float* d2 = (float*)(ws + OFF_D2);
  float* d3 = (float*)(ws + OFF_D3);
  float* d4 = (float*)(ws + OFF_D4);
  float* d5 = (float*)(ws + OFF_D5);
  float* d6 = (float*)(ws + OFF_D6);
  float* out = (float*)d_out;

  hipMemsetAsync(ws, 0, 36864, stream);  // stats + hist
  k_mode<<<1536, 256, 0, stream>>>(x, mode);
  k_hist<<<256, 256, 0, stream>>>(mode, hist);
  k_build<<<1, 256, 0, stream>>>(hist, pw1, pb1, g1, be1, pw2, pb2, g2, be2, stats, lut);
  k_conv1g<<<8 * 171, 256, 0, stream>>>(mode, lut, d1, dw);
  k_conv2_corr1<<<456 + 512, 256, 0, stream>>>(d1, d2, dw, mode, lut, stats);
  k_conv3_pair<<<152 + 512, 256, 0, stream>>>(d2, d3, dw, d1, stats);
  k_tail8<<<8 + 512, 256, 0, stream>>>(d2, d3, d4, d5, d6, dw, stats);
  k_score<<<4096, 256, 0, stream>>>(mode, lut, d1, d2, d3, d4, d5, d6, stats, sw, gs, bs, out);
}

// Round 8
// 737.561 us; speedup vs baseline: 1.1089x; 1.0023x over previous
//
#include <hip/hip_runtime.h>
#include <stdint.h>

// ---------------------------------------------------------------------------
// ColorHead: quantize -> 11x11 mode pool -> (1x1conv+BN+LReLU)x2 ->
//            6-level stride-3 conv pyramid + nearest upsample + grouped 1x1
//            + per-level train-BN -> accumulated score (8,32,512,512) fp32.
// R9: R8 (739us) minus the memset dispatch (zeroing folded into k_mode
//     blocks 0..8) + u32-vectorized k_hist. 9 -> 8 GPU ops. This round
//     doubles as the dispatch-boundary-cost discriminator.
// ---------------------------------------------------------------------------

#define NPX   2097152          // 8*512*512
#define NINV  (1.0f/2097152.0f)

// ---- workspace layout (bytes) ----
#define OFF_STATS 0            // float stats[4096]
#define OFF_HIST  16384        // uint32 hist[4913]
#define OFF_LUT   36864        // uint32 lut[4913*8]  (16 bf16 per combo)
#define OFF_MODE  194560       // uint8 mode[8*3*512*512]
#define OFF_D1    73594880     // float d1[8*16*171*171]
#define OFF_D2    88566272     // float d2[8*16*57*57]
#define OFF_D3    90229760     // float d3[8*16*19*19]
#define OFF_D4    90414592     // float d4[8*16*7*7]
#define OFF_D5    90439680     // float d5[8*16*3*3]
#define OFF_D6    90444288     // float d6[8*16*1*1]

// ---- stats region (float indices) ----
#define S_PREP    184   // 16  (+S2 at 200) — consumed by k_score
#define S2_PREP   200   // 16
#define S_Z1      216   // 16  (+S2_Z1 232, S_PZ1 248: 48 contiguous)
#define S2_Z1     232
#define S_PZ1     248
#define S_LVLBASE 264   // levels 2..6: 48 each {Sz,Sz2,Szz}

__device__ __forceinline__ uint32_t f2bf(float f) {
  uint32_t u = __float_as_uint(f);
  u += 0x7FFFu + ((u >> 16) & 1u);
  return u >> 16;
}
__device__ __forceinline__ float bf2f(uint32_t u) {
  return __uint_as_float(u << 16);
}

__device__ __forceinline__ float wave_red(float v) {
  v += __shfl_down(v, 32); v += __shfl_down(v, 16); v += __shfl_down(v, 8);
  v += __shfl_down(v, 4);  v += __shfl_down(v, 2);  v += __shfl_down(v, 1);
  return v;
}

// block = 256 threads. Reduce K per-thread partials, then atomic/store.
template<int K, bool ATOMIC>
__device__ __forceinline__ void block_red(float* acc, float* dst, float* lds) {
  int lane = threadIdx.x & 63, wid = threadIdx.x >> 6;
#pragma unroll
  for (int k = 0; k < K; ++k) {
    float v = wave_red(acc[k]);
    if (lane == 0) lds[wid * K + k] = v;
  }
  __syncthreads();
  if ((int)threadIdx.x < K) {
    float s = lds[threadIdx.x] + lds[K + threadIdx.x] + lds[2 * K + threadIdx.x] + lds[3 * K + threadIdx.x];
    if (ATOMIC) atomicAdd(&dst[threadIdx.x], s);
    else        dst[threadIdx.x] = s;
  }
}

// ---------------------------------------------------------------------------
// K1: quantize + 11x11 reflect-padded mode pool. 16-row tiles, grid 1536.
//     Blocks 0..8 additionally zero the 36 KB stats+hist region (replaces the
//     hipMemsetAsync dispatch; kernel boundary orders it before k_hist).
// ---------------------------------------------------------------------------
__global__ __launch_bounds__(256) void k_mode(const float* __restrict__ x,
                                              uint8_t* __restrict__ mode,
                                              uint32_t* __restrict__ zr) {
  int bx = blockIdx.x;
  int tid = threadIdx.x;
  if (bx < 9) {
#pragma unroll
    for (int k = 0; k < 4; ++k) zr[bx * 1024 + k * 256 + tid] = 0u;
  }
  int rb = bx & 31, cb = (bx >> 5) & 1, pl = bx >> 6;  // 32 rowblk, 2 colblk, 24 planes
  __shared__ uint8_t tile[26][272];
  const float* xp = x + (size_t)pl * 262144;
  for (int e = tid; e < 26 * 266; e += 256) {
    int lr = e / 266, lc = e - lr * 266;
    int gr = rb * 16 - 5 + lr; if (gr < 0) gr = -gr; else if (gr > 511) gr = 1022 - gr;
    int gc = cb * 256 - 5 + lc; if (gc < 0) gc = -gc; else if (gc > 511) gc = 1022 - gc;
    float v = xp[gr * 512 + gc];
    tile[lr][lc] = (uint8_t)(int)rintf((v * 255.0f) * 0.0625f);
  }
  __syncthreads();
  int t = tid;
  uint32_t h0 = 0, h1 = 0, h2 = 0, h3 = 0, h4 = 0;
#define ADDV(vv) { int v_ = (vv); uint32_t inc_ = 1u << ((v_ & 3) << 3); int w_ = v_ >> 2; \
    h0 += (w_ == 0) ? inc_ : 0u; h1 += (w_ == 1) ? inc_ : 0u; h2 += (w_ == 2) ? inc_ : 0u; \
    h3 += (w_ == 3) ? inc_ : 0u; h4 += (w_ == 4) ? inc_ : 0u; }
#define SUBV(vv) { int v_ = (vv); uint32_t inc_ = 1u << ((v_ & 3) << 3); int w_ = v_ >> 2; \
    h0 -= (w_ == 0) ? inc_ : 0u; h1 -= (w_ == 1) ? inc_ : 0u; h2 -= (w_ == 2) ? inc_ : 0u; \
    h3 -= (w_ == 3) ? inc_ : 0u; h4 -= (w_ == 4) ? inc_ : 0u; }
#define SCAN_STORE(OI) { uint32_t best_ = h0 & 255u; int bi_ = 0; uint32_t c_; \
    c_ = (h0 >> 8)  & 255u; if (c_ > best_) { best_ = c_; bi_ = 1; } \
    c_ = (h0 >> 16) & 255u; if (c_ > best_) { best_ = c_; bi_ = 2; } \
    c_ = (h0 >> 24);        if (c_ > best_) { best_ = c_; bi_ = 3; } \
    c_ = h1 & 255u;         if (c_ > best_) { best_ = c_; bi_ = 4; } \
    c_ = (h1 >> 8)  & 255u; if (c_ > best_) { best_ = c_; bi_ = 5; } \
    c_ = (h1 >> 16) & 255u; if (c_ > best_) { best_ = c_; bi_ = 6; } \
    c_ = (h1 >> 24);        if (c_ > best_) { best_ = c_; bi_ = 7; } \
    c_ = h2 & 255u;         if (c_ > best_) { best_ = c_; bi_ = 8; } \
    c_ = (h2 >> 8)  & 255u; if (c_ > best_) { best_ = c_; bi_ = 9; } \
    c_ = (h2 >> 16) & 255u; if (c_ > best_) { best_ = c_; bi_ = 10; } \
    c_ = (h2 >> 24);        if (c_ > best_) { best_ = c_; bi_ = 11; } \
    c_ = h3 & 255u;         if (c_ > best_) { best_ = c_; bi_ = 12; } \
    c_ = (h3 >> 8)  & 255u; if (c_ > best_) { best_ = c_; bi_ = 13; } \
    c_ = (h3 >> 16) & 255u; if (c_ > best_) { best_ = c_; bi_ = 14; } \
    c_ = (h3 >> 24);        if (c_ > best_) { best_ = c_; bi_ = 15; } \
    c_ = h4 & 255u;         if (c_ > best_) { best_ = c_; bi_ = 16; } \
    mode[OI] = (uint8_t)bi_; }
#pragma unroll
  for (int dy = 0; dy < 11; ++dy) {
#pragma unroll
    for (int dx = 0; dx < 11; ++dx) ADDV(tile[dy][t + dx]);
  }
  size_t ob = (size_t)pl * 262144 + (size_t)(rb * 16) * 512 + cb * 256 + t;
  SCAN_STORE(ob);
  for (int s = 1; s < 16; ++s) {
#pragma unroll
    for (int dx = 0; dx < 11; ++dx) { SUBV(tile[s - 1][t + dx]); ADDV(tile[s + 10][t + dx]); }
    SCAN_STORE(ob + (size_t)s * 512);
  }
#undef ADDV
#undef SUBV
#undef SCAN_STORE
}

// ---------------------------------------------------------------------------
// K2: histogram of 3-channel mode combos (17^3 = 4913 bins). grid 256.
//     4 pixels/thread via u32 loads.
// ---------------------------------------------------------------------------
__global__ __launch_bounds__(256) void k_hist(const uint8_t* __restrict__ mode,
                                              uint32_t* __restrict__ hist) {
  __shared__ uint32_t h[4913];
  int tid = threadIdx.x;
  for (int e = tid; e < 4913; e += 256) h[e] = 0;
  __syncthreads();
  int base = blockIdx.x * 8192;
  for (int it = 0; it < 8; ++it) {
    int px = base + it * 1024 + tid * 4;
    int b = px >> 18, rem = px & 262143;
    const uint8_t* mp = mode + (size_t)b * 786432 + rem;
    uint32_t m0 = *(const uint32_t*)(mp);
    uint32_t m1 = *(const uint32_t*)(mp + 262144);
    uint32_t m2 = *(const uint32_t*)(mp + 524288);
#pragma unroll
    for (int q = 0; q < 4; ++q) {
      int c = (int)((m0 >> (8 * q)) & 255u) + 17 * (int)((m1 >> (8 * q)) & 255u)
            + 289 * (int)((m2 >> (8 * q)) & 255u);
      atomicAdd(&h[c], 1u);
    }
  }
  __syncthreads();
  for (int e = tid; e < 4913; e += 256)
    if (h[e]) atomicAdd(&hist[e], h[e]);
}

// ---------------------------------------------------------------------------
// K3: one-block build: pre1 moments -> BN1 -> h1 moments -> BN2 -> LUT + prep
//     moments. All intermediates in LDS.
// ---------------------------------------------------------------------------
__global__ __launch_bounds__(256) void k_build(const uint32_t* __restrict__ hist,
    const float* __restrict__ pw1, const float* __restrict__ pb1,
    const float* __restrict__ g1,  const float* __restrict__ be1,
    const float* __restrict__ pw2, const float* __restrict__ pb2,
    const float* __restrict__ g2,  const float* __restrict__ be2,
    float* __restrict__ stats, uint32_t* __restrict__ lut) {
  __shared__ float red[4 * 152];
  __shared__ float sW1[48], sP1[16];     // pw1, pb1
  __shared__ float sA1[48], sB1[16];     // BN1 affine
  __shared__ float sA2[256], sB2[16];    // BN2 affine
  __shared__ float sPre[32], sH[152];    // internal moments
  int tid = threadIdx.x;
  if (tid < 48) sW1[tid] = pw1[tid];
  if (tid < 16) sP1[tid] = pb1[tid];
  __syncthreads();
  // ---- phase A: pre1 = pw1*xq + pb1 moments ----
  {
    float acc[32];
#pragma unroll
    for (int k = 0; k < 32; ++k) acc[k] = 0.f;
    for (int bin = tid; bin < 4913; bin += 256) {
      float w = (float)hist[bin];
      if (w == 0.f) continue;
      int m0 = bin % 17, r = bin / 17;
      int m1 = r % 17, m2 = r / 17;
      float x0 = m0 * 0.0625f, x1 = m1 * 0.0625f, x2 = m2 * 0.0625f;
#pragma unroll
      for (int o = 0; o < 16; ++o) {
        float p = fmaf(sW1[o * 3], x0, fmaf(sW1[o * 3 + 1], x1, fmaf(sW1[o * 3 + 2], x2, sP1[o])));
        acc[o] = fmaf(w, p, acc[o]);
        acc[16 + o] = fmaf(w * p, p, acc[16 + o]);
      }
    }
    block_red<32, false>(acc, sPre, red);
  }
  __syncthreads();
  if (tid < 16) {  // BN1 affine
    int o = tid;
    float m = sPre[o] * NINV;
    float var = sPre[16 + o] * NINV - m * m;
    float s = g1[o] * rsqrtf(var + 1e-5f);
    sA1[o * 3 + 0] = sW1[o * 3 + 0] * s;
    sA1[o * 3 + 1] = sW1[o * 3 + 1] * s;
    sA1[o * 3 + 2] = sW1[o * 3 + 2] * s;
    sB1[o] = (sP1[o] - m) * s + be1[o];
  }
  __syncthreads();
  // ---- phase B: h1 moments (16 sums + 136 upper-tri) ----
  {
    float acc[152];
#pragma unroll
    for (int k = 0; k < 152; ++k) acc[k] = 0.f;
    for (int bin = tid; bin < 4913; bin += 256) {
      float w = (float)hist[bin];
      if (w == 0.f) continue;
      int m0 = bin % 17, r = bin / 17;
      int m1 = r % 17, m2 = r / 17;
      float x0 = m0 * 0.0625f, x1 = m1 * 0.0625f, x2 = m2 * 0.0625f;
      float h[16];
#pragma unroll
      for (int c = 0; c < 16; ++c) {
        float y = fmaf(sA1[c * 3], x0, fmaf(sA1[c * 3 + 1], x1,
                  fmaf(sA1[c * 3 + 2], x2, sB1[c])));
        h[c] = fmaxf(y, 0.01f * y);
        acc[c] = fmaf(w, h[c], acc[c]);
      }
#pragma unroll
      for (int c = 0; c < 16; ++c) {
#pragma unroll
        for (int c2 = c; c2 < 16; ++c2) {
          int idx = 16 * c - (c * (c - 1)) / 2 + (c2 - c);
          acc[16 + idx] = fmaf(w * h[c], h[c2], acc[16 + idx]);
        }
      }
    }
    block_red<152, false>(acc, sH, red);
  }
  __syncthreads();
  if (tid < 16) {  // BN2 affine
    int o = tid;
    float s1 = 0.f;
#pragma unroll
    for (int c = 0; c < 16; ++c) s1 = fmaf(pw2[o * 16 + c], sH[c] * NINV, s1);
    float e2 = 0.f;
#pragma unroll
    for (int c = 0; c < 16; ++c) {
#pragma unroll
      for (int c2 = 0; c2 < 16; ++c2) {
        int lo = c < c2 ? c : c2, hi = c < c2 ? c2 : c;
        int idx = 16 * lo - (lo * (lo - 1)) / 2 + (hi - lo);
        e2 = fmaf(pw2[o * 16 + c] * pw2[o * 16 + c2], sH[16 + idx] * NINV, e2);
      }
    }
    float var = e2 - s1 * s1;
    float mean = s1 + pb2[o];
    float s = g2[o] * rsqrtf(var + 1e-5f);
#pragma unroll
    for (int c = 0; c < 16; ++c) sA2[o * 16 + c] = pw2[o * 16 + c] * s;
    sB2[o] = (pb2[o] - mean) * s + be2[o];
  }
  __syncthreads();
  // ---- phase C: LUT (bf16-packed prep per combo) + prep moments ----
  {
    float acc[32];
#pragma unroll
    for (int k = 0; k < 32; ++k) acc[k] = 0.f;
    for (int bin = tid; bin < 4913; bin += 256) {
      float w = (float)hist[bin];
      int m0 = bin % 17, r = bin / 17;
      int m1 = r % 17, m2 = r / 17;
      float x0 = m0 * 0.0625f, x1 = m1 * 0.0625f, x2 = m2 * 0.0625f;
      float h[16];
#pragma unroll
      for (int c = 0; c < 16; ++c) {
        float y = fmaf(sA1[c * 3], x0, fmaf(sA1[c * 3 + 1], x1,
                  fmaf(sA1[c * 3 + 2], x2, sB1[c])));
        h[c] = fmaxf(y, 0.01f * y);
      }
      float p[16];
#pragma unroll
      for (int o = 0; o < 16; ++o) {
        float y = sB2[o];
#pragma unroll
        for (int c = 0; c < 16; ++c) y = fmaf(sA2[o * 16 + c], h[c], y);
        p[o] = fmaxf(y, 0.01f * y);
        acc[o] = fmaf(w, p[o], acc[o]);
        acc[16 + o] = fmaf(w * p[o], p[o], acc[16 + o]);
      }
#pragma unroll
      for (int d = 0; d < 8; ++d)
        lut[bin * 8 + d] = f2bf(p[2 * d]) | (f2bf(p[2 * d + 1]) << 16);
    }
    block_red<32, false>(acc, stats + S_PREP, red);
  }
}

// ---------------------------------------------------------------------------
// conv body: 3x3 stride 3 pad 1, 16->16 channels, fp32 in/out.
// ---------------------------------------------------------------------------
template<int HIN, int WIN, int HOUT, int WOUT>
__device__ __forceinline__ void conv_body(const float* __restrict__ in,
                                          float* __restrict__ out,
                                          const float* __restrict__ dw, int bx) {
  __shared__ float tile[3][16][WIN + 2];
  int r = bx % HOUT, b = bx / HOUT;
  int tid = threadIdx.x;
  for (int e = tid; e < 48; e += 256) { tile[e / 16][e & 15][0] = 0.f; tile[e / 16][e & 15][WIN + 1] = 0.f; }
  for (int e = tid; e < 3 * 16 * WIN; e += 256) {
    int ky = e / (16 * WIN); int rem = e - ky * (16 * WIN); int ic = rem / WIN; int col = rem - ic * WIN;
    int gr = 3 * r - 1 + ky;
    float v = 0.f;
    if (gr >= 0 && gr < HIN) v = in[((size_t)(b * 16 + ic) * HIN + gr) * WIN + col];
    tile[ky][ic][col + 1] = v;
  }
  __syncthreads();
  int c = tid;
  if (c < WOUT) {
    float acc[16];
#pragma unroll
    for (int o = 0; o < 16; ++o) acc[o] = 0.f;
#pragma unroll
    for (int ic = 0; ic < 16; ++ic) {
      float v[9];
#pragma unroll
      for (int ky = 0; ky < 3; ++ky) {
#pragma unroll
        for (int kx = 0; kx < 3; ++kx) v[ky * 3 + kx] = tile[ky][ic][3 * c + kx];
      }
#pragma unroll
      for (int o = 0; o < 16; ++o) {
        const float* w = dw + (o * 16 + ic) * 9;
#pragma unroll
        for (int tp = 0; tp < 9; ++tp) acc[o] = fmaf(v[tp], w[tp], acc[o]);
      }
    }
#pragma unroll
    for (int o = 0; o < 16; ++o)
      out[((size_t)(b * 16 + o) * HOUT + r) * WOUT + c] = acc[o];
  }
}

// pair stats body: Sz, Sz^2, S(z_{l-1} z_l) over dst grid. 512 blocks' worth.
template<int HP, int HZ>
__device__ __forceinline__ void pair_body(const float* __restrict__ dp,
                                          const float* __restrict__ dz,
                                          float* __restrict__ dst, int bx) {
  int g = bx & 15, b = (bx >> 4) & 7, jq = bx >> 7;
  const float* dpp = dp + (size_t)(b * 16 + g) * HP * HP;
  const float* dzp = dz + (size_t)(b * 16 + g) * HZ * HZ;
  float a1 = 0.f, a2 = 0.f, a3 = 0.f;
  for (int j = jq * 128; j < jq * 128 + 128; ++j) {
    int r1 = (j * HP) >> 9, r2 = (j * HZ) >> 9;
    const float* rp = dpp + r1 * HP;
    const float* rz = dzp + r2 * HZ;
    for (int i = threadIdx.x; i < 512; i += 256) {
      int c1 = (i * HP) >> 9, c2 = (i * HZ) >> 9;
      float zp = rp[c1], zz = rz[c2];
      a1 += zz; a2 = fmaf(zz, zz, a2); a3 = fmaf(zp, zz, a3);
    }
  }
  a1 = wave_red(a1); a2 = wave_red(a2); a3 = wave_red(a3);
  __shared__ float red[12];
  int lane = threadIdx.x & 63, wid = threadIdx.x >> 6;
  if (!lane) { red[wid * 3] = a1; red[wid * 3 + 1] = a2; red[wid * 3 + 2] = a3; }
  __syncthreads();
  if (threadIdx.x < 3) {
    float s = red[threadIdx.x] + red[3 + threadIdx.x] + red[6 + threadIdx.x] + red[9 + threadIdx.x];
    atomicAdd(&dst[threadIdx.x * 16 + g], s);
  }
}

// level-1 stats body: Sz1, Sz1^2, S(prep*z1); prep gathered from mode+LUT.
__device__ __forceinline__ void corr1_body(const uint8_t* __restrict__ mode,
                                           const uint32_t* __restrict__ lut,
                                           const float* __restrict__ d1,
                                           float* __restrict__ stats, int bx) {
  int b = bx >> 6, band = bx & 63;
  float acc[48];
#pragma unroll
  for (int k = 0; k < 48; ++k) acc[k] = 0.f;
  for (int jj = 0; jj < 8; ++jj) {
    int j = band * 8 + jj;
    int r1 = (j * 171) >> 9;
#pragma unroll
    for (int ii = 0; ii < 2; ++ii) {
      int i = (int)threadIdx.x + ii * 256;
      int c1 = (i * 171) >> 9;
      const uint8_t* mp = mode + (size_t)b * 786432 + j * 512 + i;
      int combo = (int)mp[0] + 17 * (int)mp[262144] + 289 * (int)mp[524288];
      const uint4* L = (const uint4*)(lut + combo * 8);
      uint4 q0 = L[0], q1 = L[1];
      uint32_t q[8] = {q0.x, q0.y, q0.z, q0.w, q1.x, q1.y, q1.z, q1.w};
#pragma unroll
      for (int g = 0; g < 16; ++g) {
        float p = bf2f((g & 1) ? (q[g >> 1] >> 16) : (q[g >> 1] & 0xFFFFu));
        float z = d1[((size_t)(b * 16 + g) * 171 + r1) * 171 + c1];
        acc[g] += z; acc[16 + g] = fmaf(z, z, acc[16 + g]); acc[32 + g] = fmaf(p, z, acc[32 + g]);
      }
    }
  }
  __shared__ float red[4 * 48];
  block_red<48, true>(acc, stats + S_Z1, red);
}

// ---------------------------------------------------------------------------
// K4: level-1 conv, input gathered from mode+LUT (bf16 LUT lines, L2-resident).
// ---------------------------------------------------------------------------
__global__ __launch_bounds__(256) void k_conv1g(const uint8_t* __restrict__ mode,
                                                const uint32_t* __restrict__ lut,
                                                float* __restrict__ out,
                                                const float* __restrict__ dw) {
  __shared__ uint16_t tile[3][16][514];
  int bx = blockIdx.x; int r = bx % 171, b = bx / 171;
  int tid = threadIdx.x;
  for (int e = tid; e < 48; e += 256) { tile[e / 16][e & 15][0] = 0; tile[e / 16][e & 15][513] = 0; }
  for (int e = tid; e < 3 * 512; e += 256) {
    int ky = e >> 9, col = e & 511;
    int gr = 3 * r - 1 + ky;
    if (gr < 0 || gr > 511) {
#pragma unroll
      for (int c = 0; c < 16; ++c) tile[ky][c][col + 1] = 0;
    } else {
      const uint8_t* mp = mode + (size_t)b * 786432 + gr * 512 + col;
      int combo = (int)mp[0] + 17 * (int)mp[262144] + 289 * (int)mp[524288];
      const uint4* L = (const uint4*)(lut + combo * 8);
      uint4 q0 = L[0], q1 = L[1];
      uint32_t q[8] = {q0.x, q0.y, q0.z, q0.w, q1.x, q1.y, q1.z, q1.w};
#pragma unroll
      for (int d = 0; d < 8; ++d) {
        tile[ky][2 * d][col + 1]     = (uint16_t)(q[d] & 0xFFFFu);
        tile[ky][2 * d + 1][col + 1] = (uint16_t)(q[d] >> 16);
      }
    }
  }
  __syncthreads();
  int c = tid;
  if (c < 171) {
    float acc[16];
#pragma unroll
    for (int o = 0; o < 16; ++o) acc[o] = 0.f;
#pragma unroll
    for (int ic = 0; ic < 16; ++ic) {
      float v[9];
#pragma unroll
      for (int ky = 0; ky < 3; ++ky) {
#pragma unroll
        for (int kx = 0; kx < 3; ++kx)
          v[ky * 3 + kx] = __uint_as_float(((uint32_t)tile[ky][ic][3 * c + kx]) << 16);
      }
#pragma unroll
      for (int o = 0; o < 16; ++o) {
        const float* w = dw + (o * 16 + ic) * 9;
#pragma unroll
        for (int tp = 0; tp < 9; ++tp) acc[o] = fmaf(v[tp], w[tp], acc[o]);
      }
    }
#pragma unroll
    for (int o = 0; o < 16; ++o)
      out[((size_t)(b * 16 + o) * 171 + r) * 171 + c] = acc[o];
  }
}

// K5: conv level 2 (456 blocks) + corr1 stats (512 blocks) in one dispatch.
__global__ __launch_bounds__(256) void k_conv2_corr1(const float* __restrict__ d1,
    float* __restrict__ d2, const float* __restrict__ dw,
    const uint8_t* __restrict__ mode, const uint32_t* __restrict__ lut,
    float* __restrict__ stats) {
  if ((int)blockIdx.x < 456) conv_body<171, 171, 57, 57>(d1, d2, dw, (int)blockIdx.x);
  else                       corr1_body(mode, lut, d1, stats, (int)blockIdx.x - 456);
}

// K6: conv level 3 (152 blocks) + pair stats for level 2 (512 blocks).
__global__ __launch_bounds__(256) void k_conv3_pair(const float* __restrict__ d2,
    float* __restrict__ d3, const float* __restrict__ dw,
    const float* __restrict__ d1, float* __restrict__ stats) {
  if ((int)blockIdx.x < 152) conv_body<57, 57, 19, 19>(d2, d3, dw, (int)blockIdx.x);
  else                       pair_body<171, 57>(d1, d2, stats + S_LVLBASE, (int)blockIdx.x - 152);
}

// ---------------------------------------------------------------------------
// K7: k_tail8: blocks 0..7 = per-batch {conv4, pair4-exact, conv5, pair5-exact,
//     conv6, pair6-closed} with dw cached in LDS; blocks 8..519 = pair<57,19>
//     rider for level-3 stats.
// ---------------------------------------------------------------------------
__global__ __launch_bounds__(256) void k_tail8(const float* __restrict__ d2,
    const float* __restrict__ d3, float* __restrict__ d4, float* __restrict__ d5,
    float* __restrict__ d6, const float* __restrict__ dw, float* __restrict__ stats) {
  int bx = blockIdx.x;
  if (bx >= 8) { pair_body<57, 19>(d2, d3, stats + S_LVLBASE + 48, bx - 8); return; }
  __shared__ float s3[16][19][19];
  __shared__ float s4[16][7][7];
  __shared__ float s5[16][3][3];
  __shared__ float s6[16];
  __shared__ float dwS[2304];
  __shared__ float acc[144];   // {Sz4,Sz4²,Sz3z4}[48] {z5..}[48] {z6..}[48]
  int tid = threadIdx.x, b = bx;
  for (int e = tid; e < 2304; e += 256) dwS[e] = dw[e];
  for (int e = tid; e < 144; e += 256) acc[e] = 0.f;
  for (int e = tid; e < 16 * 361; e += 256) ((float*)s3)[e] = d3[(size_t)b * 5776 + e];
  __syncthreads();
  // conv4: d3(19) -> d4(7)
  for (int e = tid; e < 784; e += 256) {
    int o = e / 49, rc = e - o * 49; int r = rc / 7, c = rc % 7;
    float a = 0.f;
#pragma unroll
    for (int ic = 0; ic < 16; ++ic) {
      const float* w = dwS + (o * 16 + ic) * 9;
#pragma unroll
      for (int ky = 0; ky < 3; ++ky) {
        int gr = 3 * r - 1 + ky; if (gr < 0 || gr > 18) continue;
#pragma unroll
        for (int kx = 0; kx < 3; ++kx) {
          int gc = 3 * c - 1 + kx; if (gc < 0 || gc > 18) continue;
          a = fmaf(s3[ic][gr][gc], w[ky * 3 + kx], a);
        }
      }
    }
    s4[o][r][c] = a; d4[((size_t)(b * 16 + o) * 7 + r) * 7 + c] = a;
  }
  __syncthreads();
  // pair4 (19 -> 7) exact counts ; conv5: s4 -> s5, d5
  for (int e = tid; e < 784; e += 256) {
    int g = e & 15, rc = e >> 4; int r2 = rc / 7, c2 = rc % 7;
    int loZ = (512 * r2 + 6) / 7, hiZ = (512 * (r2 + 1) + 6) / 7;
    int loC = (512 * c2 + 6) / 7, hiC = (512 * (c2 + 1) + 6) / 7;
    int rrmin = (loZ * 19) >> 9, rrmax = ((hiZ - 1) * 19) >> 9;
    int ccmin = (loC * 19) >> 9, ccmax = ((hiC - 1) * 19) >> 9;
    float z = s4[g][r2][c2];
    float B = 0.f;
    for (int rr = rrmin; rr <= rrmax; ++rr) {
      int loP = (512 * rr + 18) / 19, hiP = (512 * (rr + 1) + 18) / 19;
      int cntR = min(hiP, hiZ) - max(loP, loZ); if (cntR <= 0) continue;
      float rowS = 0.f;
      for (int cc = ccmin; cc <= ccmax; ++cc) {
        int loQ = (512 * cc + 18) / 19, hiQ = (512 * (cc + 1) + 18) / 19;
        int cntC = min(hiQ, hiC) - max(loQ, loC); if (cntC <= 0) continue;
        rowS = fmaf((float)cntC, s3[g][rr][cc], rowS);
      }
      B = fmaf((float)cntR, rowS, B);
    }
    float wgt = (float)((hiZ - loZ) * (hiC - loC));
    atomicAdd(&acc[g], wgt * z);
    atomicAdd(&acc[16 + g], wgt * z * z);
    atomicAdd(&acc[32 + g], B * z);
  }
  for (int e = tid; e < 144; e += 256) {
    int o = e / 9, rc = e - o * 9; int r = rc / 3, c = rc % 3;
    float a = 0.f;
#pragma unroll
    for (int ic = 0; ic < 16; ++ic) {
      const float* w = dwS + (o * 16 + ic) * 9;
#pragma unroll
      for (int ky = 0; ky < 3; ++ky) {
        int gr = 3 * r - 1 + ky; if (gr < 0 || gr > 6) continue;
#pragma unroll
        for (int kx = 0; kx < 3; ++kx) {
          int gc = 3 * c - 1 + kx; if (gc < 0 || gc > 6) continue;
          a = fmaf(s4[ic][gr][gc], w[ky * 3 + kx], a);
        }
      }
    }
    s5[o][r][c] = a; d5[((size_t)(b * 16 + o) * 3 + r) * 3 + c] = a;
  }
  __syncthreads();
  // pair5 (7 -> 3) exact counts ; conv6: s5 -> s6, d6
  for (int e = tid; e < 144; e += 256) {
    int g = e & 15, rc = e >> 4; int r2 = rc / 3, c2 = rc % 3;
    int loZ = (512 * r2 + 2) / 3, hiZ = (512 * (r2 + 1) + 2) / 3;
    int loC = (512 * c2 + 2) / 3, hiC = (512 * (c2 + 1) + 2) / 3;
    int rrmin = (loZ * 7) >> 9, rrmax = ((hiZ - 1) * 7) >> 9;
    int ccmin = (loC * 7) >> 9, ccmax = ((hiC - 1) * 7) >> 9;
    float z = s5[g][r2][c2];
    float B = 0.f;
    for (int rr = rrmin; rr <= rrmax; ++rr) {
      int loP = (512 * rr + 6) / 7, hiP = (512 * (rr + 1) + 6) / 7;
      int cntR = min(hiP, hiZ) - max(loP, loZ); if (cntR <= 0) continue;
      float rowS = 0.f;
      for (int cc = ccmin; cc <= ccmax; ++cc) {
        int loQ = (512 * cc + 6) / 7, hiQ = (512 * (cc + 1) + 6) / 7;
        int cntC = min(hiQ, hiC) - max(loQ, loC); if (cntC <= 0) continue;
        rowS = fmaf((float)cntC, s4[g][rr][cc], rowS);
      }
      B = fmaf((float)cntR, rowS, B);
    }
    float wgt = (float)((hiZ - loZ) * (hiC - loC));
    atomicAdd(&acc[48 + g], wgt * z);
    atomicAdd(&acc[64 + g], wgt * z * z);
    atomicAdd(&acc[80 + g], B * z);
  }
  if (tid < 16) {
    int o = tid; float a = 0.f;
#pragma unroll
    for (int ic = 0; ic < 16; ++ic) {
      const float* w = dwS + (o * 16 + ic) * 9;
#pragma unroll
      for (int ky = 1; ky < 3; ++ky)
#pragma unroll
        for (int kx = 1; kx < 3; ++kx)
          a = fmaf(s5[ic][ky - 1][kx - 1], w[ky * 3 + kx], a);
    }
    s6[o] = a; d6[b * 16 + o] = a;
  }
  __syncthreads();
  // pair6 (3 -> 1) closed form: z6 constant; nearest weights 171/171/170
  if (tid < 16) {
    int g = tid; float z6 = s6[g];
    const float wr3[3] = {171.f, 171.f, 170.f};
    float s5s = 0.f;
#pragma unroll
    for (int r = 0; r < 3; ++r)
#pragma unroll
      for (int c = 0; c < 3; ++c) s5s = fmaf(wr3[r] * wr3[c], s5[g][r][c], s5s);
    acc[96 + g]  += 262144.f * z6;
    acc[112 + g] += 262144.f * z6 * z6;
    acc[128 + g] += z6 * s5s;
  }
  __syncthreads();
  for (int e = tid; e < 144; e += 256)
    atomicAdd(&stats[S_LVLBASE + 96 + e], acc[e]);
}

// ---------------------------------------------------------------------------
// K8: fused score: BN affines computed in-block from raw sums, then all 6
//     levels in one pass. grid 4096 = (b, row j).
// ---------------------------------------------------------------------------
__global__ __launch_bounds__(256) void k_score(const uint8_t* __restrict__ mode,
    const uint32_t* __restrict__ lut,
    const float* __restrict__ d1, const float* __restrict__ d2, const float* __restrict__ d3,
    const float* __restrict__ d4, const float* __restrict__ d5, const float* __restrict__ d6,
    const float* __restrict__ stats, const float* __restrict__ sw,
    const float* __restrict__ gs, const float* __restrict__ bs,
    float* __restrict__ out) {
  __shared__ float zrow[4128];
  __shared__ float aff[576];
  __shared__ uint16_t prow[16][512];
  int bx = blockIdx.x; int b = bx >> 9, j = bx & 511;
  int tid = threadIdx.x;
  // BN affines from raw sums (~25 flops/thread, redundant per block but free)
  if (tid < 192) {
    int lvl = tid >> 5, ch = tid & 31, g = ch >> 1, o = ch & 1;
    float Sp, Sp2, Sz, Sz2, Spz;
    if (lvl == 0) {
      Sp = stats[S_PREP + g]; Sp2 = stats[S2_PREP + g];
      Sz = stats[S_Z1 + g];   Sz2 = stats[S2_Z1 + g]; Spz = stats[S_PZ1 + g];
    } else {
      int base = S_LVLBASE + (lvl - 1) * 48;
      Sz = stats[base + g]; Sz2 = stats[base + 16 + g]; Spz = stats[base + 32 + g];
      if (lvl == 1) { Sp = stats[S_Z1 + g]; Sp2 = stats[S2_Z1 + g]; }
      else { int pb = S_LVLBASE + (lvl - 2) * 48; Sp = stats[pb + g]; Sp2 = stats[pb + 16 + g]; }
    }
    float mp = Sp * NINV, mz = Sz * NINV;
    float ep2 = Sp2 * NINV, ez2 = Sz2 * NINV, epz = Spz * NINV;
    float w0 = sw[g * 4 + o * 2], w1 = sw[g * 4 + o * 2 + 1];
    float mean = w0 * mp + w1 * mz;
    float e2 = w0 * w0 * ep2 + 2.f * w0 * w1 * epz + w1 * w1 * ez2;
    float var = e2 - mean * mean;
    float s = gs[ch] * rsqrtf(var + 1e-5f);
    aff[(lvl * 32 + ch) * 3 + 0] = s * w0;
    aff[(lvl * 32 + ch) * 3 + 1] = s * w1;
    aff[(lvl * 32 + ch) * 3 + 2] = bs[ch] - mean * s;
  }
  {
    const uint8_t* mp = mode + (size_t)b * 786432 + j * 512 + tid * 2;
    uint32_t m0 = *(const uint16_t*)(mp);
    uint32_t m1 = *(const uint16_t*)(mp + 262144);
    uint32_t m2 = *(const uint16_t*)(mp + 524288);
    int ca = (int)(m0 & 255u) + 17 * (int)(m1 & 255u) + 289 * (int)(m2 & 255u);
    int cb = (int)(m0 >> 8)   + 17 * (int)(m1 >> 8)   + 289 * (int)(m2 >> 8);
    const uint4* La = (const uint4*)(lut + ca * 8);
    const uint4* Lb = (const uint4*)(lut + cb * 8);
    uint4 a0 = La[0], a1 = La[1], b0 = Lb[0], b1 = Lb[1];
    uint32_t pa[8] = {a0.x, a0.y, a0.z, a0.w, a1.x, a1.y, a1.z, a1.w};
    uint32_t pb[8] = {b0.x, b0.y, b0.z, b0.w, b1.x, b1.y, b1.z, b1.w};
    uint32_t* pr32 = (uint32_t*)prow;
#pragma unroll
    for (int c = 0; c < 16; ++c) {
      uint32_t lo = (c & 1) ? (pa[c >> 1] >> 16)         : (pa[c >> 1] & 0xFFFFu);
      uint32_t hi = (c & 1) ? (pb[c >> 1] & 0xFFFF0000u) : (pb[c >> 1] << 16);
      pr32[c * 256 + tid] = lo | hi;
    }
  }
  { int r = (j * 171) >> 9; for (int e = tid; e < 16 * 171; e += 256) { int g = e / 171, c = e - g * 171; zrow[e]        = d1[((size_t)(b * 16 + g) * 171 + r) * 171 + c]; } }
  { int r = (j * 57)  >> 9; for (int e = tid; e < 16 * 57;  e += 256) { int g = e / 57,  c = e - g * 57;  zrow[2736 + e] = d2[((size_t)(b * 16 + g) * 57  + r) * 57  + c]; } }
  { int r = (j * 19)  >> 9; for (int e = tid; e < 16 * 19;  e += 256) { int g = e / 19,  c = e - g * 19;  zrow[3648 + e] = d3[((size_t)(b * 16 + g) * 19  + r) * 19  + c]; } }
  { int r = (j * 7)   >> 9; for (int e = tid; e < 16 * 7;   e += 256) { int g = e / 7,   c = e - g * 7;   zrow[3952 + e] = d4[((size_t)(b * 16 + g) * 7   + r) * 7   + c]; } }
  { int r = (j * 3)   >> 9; for (int e = tid; e < 16 * 3;   e += 256) { int g = e / 3,   c = e - g * 3;   zrow[4064 + e] = d5[((size_t)(b * 16 + g) * 3   + r) * 3   + c]; } }
  { for (int e = tid; e < 16; e += 256) zrow[4112 + e] = d6[b * 16 + e]; }
  __syncthreads();
  int wave = tid >> 6, lane = tid & 63;
#pragma unroll
  for (int gi = 0; gi < 4; ++gi) {
    int g = wave * 4 + gi;
    float A[36];
#pragma unroll
    for (int l = 0; l < 6; ++l) {
#pragma unroll
      for (int q = 0; q < 6; ++q) A[l * 6 + q] = aff[(l * 32 + 2 * g) * 3 + q];
    }
    float z6 = zrow[4112 + g];
    const uint16_t* prow_g = &prow[g][0];
    float* orow = out + ((size_t)(b * 32 + 2 * g) * 512 + j) * 512;
    const float* z1p = zrow + g * 171;
    const float* z2p = zrow + 2736 + g * 57;
    const float* z3p = zrow + 3648 + g * 19;
    const float* z4p = zrow + 3952 + g * 7;
    const float* z5p = zrow + 4064 + g * 3;
#pragma unroll
    for (int k = 0; k < 4; ++k) {
      int i = (lane << 1) + (k << 7);
      uint32_t pv = *(const uint32_t*)(prow_g + i);
      float pA = bf2f(pv & 0xFFFFu), pB = bf2f(pv >> 16);
      int ib = i + 1;
      float za1 = z1p[(i * 171) >> 9], zb1 = z1p[(ib * 171) >> 9];
      float za2 = z2p[(i * 57) >> 9],  zb2 = z2p[(ib * 57) >> 9];
      float za3 = z3p[(i * 19) >> 9],  zb3 = z3p[(ib * 19) >> 9];
      float za4 = z4p[(i * 7) >> 9],   zb4 = z4p[(ib * 7) >> 9];
      float za5 = z5p[(i * 3) >> 9],   zb5 = z5p[(ib * 3) >> 9];
      float o0a = 0.f, o1a = 0.f, prevA = pA;
      float o0b = 0.f, o1b = 0.f, prevB = pB;
#define ST(L, ZA, ZB) { float y_; \
      y_ = fmaf(A[L*6+0], prevA, fmaf(A[L*6+1], (ZA), A[L*6+2])); o0a += fmaxf(y_, 0.01f * y_); \
      y_ = fmaf(A[L*6+3], prevA, fmaf(A[L*6+4], (ZA), A[L*6+5])); o1a += fmaxf(y_, 0.01f * y_); \
      y_ = fmaf(A[L*6+0], prevB, fmaf(A[L*6+1], (ZB), A[L*6+2])); o0b += fmaxf(y_, 0.01f * y_); \
      y_ = fmaf(A[L*6+3], prevB, fmaf(A[L*6+4], (ZB), A[L*6+5])); o1b += fmaxf(y_, 0.01f * y_); \
      prevA = (ZA); prevB = (ZB); }
      ST(0, za1, zb1) ST(1, za2, zb2) ST(2, za3, zb3) ST(3, za4, zb4) ST(4, za5, zb5) ST(5, z6, z6)
#undef ST
      float2 s0 = make_float2(o0a, o0b);
      float2 s1 = make_float2(o1a, o1b);
      *(float2*)(orow + i) = s0;
      *(float2*)(orow + 262144 + i) = s1;
    }
  }
}

// ---------------------------------------------------------------------------
extern "C" void kernel_launch(void* const* d_in, const int* in_sizes, int n_in,
                              void* d_out, int out_size, void* d_ws, size_t ws_size,
                              hipStream_t stream) {
  const float* x   = (const float*)d_in[0];
  const float* pw1 = (const float*)d_in[1];
  const float* pb1 = (const float*)d_in[2];
  const float* g1  = (const float*)d_in[3];
  const float* be1 = (const float*)d_in[4];
  const float* pw2 = (const float*)d_in[5];
  const float* pb2 = (const float*)d_in[6];
  const float* g2  = (const float*)d_in[7];
  const float* be2 = (const float*)d_in[8];
  const float* dw  = (const float*)d_in[9];
  const float* sw  = (const float*)d_in[10];
  const float* gs  = (const float*)d_in[11];
  const float* bs  = (const float*)d_in[12];
  char* ws = (char*)d_ws;
  float*    stats = (float*)(ws + OFF_STATS);
  uint32_t* hist  = (uint32_t*)(ws + OFF_HIST);
  uint32_t* lut   = (uint32_t*)(ws + OFF_LUT);
  uint8_t*  mode  = (uint8_t*)(ws + OFF_MODE);
  float* d1 = (float*)(ws + OFF_D1);
  float* d2 = (float*)(ws + OFF_D2);
  float* d3 = (float*)(ws + OFF_D3);
  float* d4 = (float*)(ws + OFF_D4);
  float* d5 = (float*)(ws + OFF_D5);
  float* d6 = (float*)(ws + OFF_D6);
  float* out = (float*)d_out;

  k_mode<<<1536, 256, 0, stream>>>(x, mode, (uint32_t*)ws);   // also zeroes stats+hist
  k_hist<<<256, 256, 0, stream>>>(mode, hist);
  k_build<<<1, 256, 0, stream>>>(hist, pw1, pb1, g1, be1, pw2, pb2, g2, be2, stats, lut);
  k_conv1g<<<8 * 171, 256, 0, stream>>>(mode, lut, d1, dw);
  k_conv2_corr1<<<456 + 512, 256, 0, stream>>>(d1, d2, dw, mode, lut, stats);
  k_conv3_pair<<<152 + 512, 256, 0, stream>>>(d2, d3, dw, d1, stats);
  k_tail8<<<8 + 512, 256, 0, stream>>>(d2, d3, d4, d5, d6, dw, stats);
  k_score<<<4096, 256, 0, stream>>>(mode, lut, d1, d2, d3, d4, d5, d6, stats, sw, gs, bs, out);
}